// Round 11
// baseline (2179.656 us; speedup 1.0000x reference)
//
#include <hip/hip_runtime.h>

// Dims fixed by the reference
#define LAY 2
#define BATCH 64
#define TMAX 512
#define DIM 256
#define AST 264    // LDS activation row stride (bytes, fp8)
#define CHUNK 16   // pipeline handoff granularity (timesteps)

typedef float floatx4 __attribute__((ext_vector_type(4)));
typedef __bf16 bf16x8 __attribute__((ext_vector_type(8)));
#define MFMA_FP8  __builtin_amdgcn_mfma_f32_16x16x32_fp8_fp8
#define MFMA_BF16 __builtin_amdgcn_mfma_f32_16x16x32_bf16

// LDS-only barrier: orders ds ops (lgkmcnt) without draining vmcnt.
#define BAR_LDS() asm volatile("s_waitcnt lgkmcnt(0)\n\ts_barrier" ::: "memory")

// d_ws layout (requires ws >= ~74 MB)
#define OFF_WPW 0x60000     // bf16 B-frag W-mats, 6 x 128 KB  (ends 0x120000)
#define OFF_FLG 0x150000    // [0..1] scan0 pair flags, [4..19] projB flags,
                            // [32..159] projA chunk counters (bg*32+chunk)
#define OFF_XP  0x200000    // layer-0 X-projections fp8, 25.2 MB
#define OFF_HP  0x1C00000   // layer-1 input projections fp8, 25.2 MB
#define OFF_HN  0x3600000   // hn0 bf16 [b*512+t][256], 16.8 MB

__device__ __forceinline__ unsigned short f2bf(float f) {
    unsigned int u = __float_as_uint(f);
    unsigned int r = u + 0x7fffu + ((u >> 16) & 1u);  // RNE
    return (unsigned short)(r >> 16);
}
__device__ __forceinline__ unsigned int pk2(float a, float b) {
    return (unsigned int)__builtin_amdgcn_cvt_pk_fp8_f32(a, b, 0, false);  // OCP e4m3 x2
}
__device__ __forceinline__ unsigned char f2q(float a) { return (unsigned char)(pk2(a, a) & 0xff); }
__device__ __forceinline__ void unp4(unsigned int u, float* f) {
    auto lo = __builtin_amdgcn_cvt_pk_f32_fp8((int)u, false);
    auto hi = __builtin_amdgcn_cvt_pk_f32_fp8((int)u, true);
    f[0] = lo[0]; f[1] = lo[1]; f[2] = hi[0]; f[3] = hi[1];
}
// sigmoid via raw v_rcp_f32 (1 instr vs ~10-instr IEEE div sequence).
__device__ __forceinline__ float sigf(float x) {
    return __builtin_amdgcn_rcpf(1.f + __expf(-x));
}
// tanh(y) = 2*sigmoid(2y) - 1
__device__ __forceinline__ float tanhfast2y(float twoy) { return 2.f * sigf(twoy) - 1.f; }

// agent-scope relaxed store: device-coherent at the LLC (projA XP path only)
__device__ __forceinline__ void ast_u32(unsigned int* p, unsigned int v) {
    __hip_atomic_store(p, v, __ATOMIC_RELAXED, __HIP_MEMORY_SCOPE_AGENT);
}

// ---------------------------------------------------------------------------
// Weight prep (identical math). Zeroes flags+counters (192 ints) and d_out.
// ---------------------------------------------------------------------------
__global__ void prep_weights(const float* __restrict__ Wz, const float* __restrict__ Wr,
                             const float* __restrict__ Wh, const float* __restrict__ Uz,
                             const float* __restrict__ Ur, const float* __restrict__ Uh,
                             unsigned char* __restrict__ ws, float* __restrict__ out) {
    int T = blockIdx.x * 256 + threadIdx.x;  // 1536*256 = 393216
    if (T == 0) out[0] = 0.f;
    if (T < 192) ((int*)(ws + OFF_FLG))[T] = 0;  // flags + projA counters
    if (T < 196608) {  // U-mats, fp8
        int e = T & 3, half = (T >> 2) & 1, lane = (T >> 3) & 63;
        int kp = (T >> 9) & 3, nt = (T >> 11) & 15, mu = T >> 15;
        int g = mu % 3, l = mu / 3;
        const float* s = (g == 0 ? Uz : g == 1 ? Ur : Uh) + l * 65536;
        int n  = nt * 16 + (lane & 15);
        int k0 = (2 * kp + half) * 32 + (lane >> 4) * 8 + 2 * e;
        float w0 = s[(k0 << 8) + n] * 8.f;        // x8: dodge e4m3 denormals
        float w1 = s[((k0 + 1) << 8) + n] * 8.f;  // undone by 0.125 post-acc
        int addr = ((mu * 16 + nt) * 4 + kp) * 1024 + lane * 16 + half * 8 + 2 * e;
        *(unsigned short*)(ws + addr) = (unsigned short)(pk2(w0, w1) & 0xffff);
    } else {           // W-mats, bf16
        int T2 = T - 196608;
        int e = T2 & 3, lane = (T2 >> 2) & 63;
        int kf = (T2 >> 8) & 7, nt = (T2 >> 11) & 15, mw = T2 >> 15;
        int g = mw % 3, l = mw / 3;
        const float* s = (g == 0 ? Wz : g == 1 ? Wr : Wh) + l * 65536;
        int n  = nt * 16 + (lane & 15);
        int k0 = kf * 32 + (lane >> 4) * 8 + 2 * e;
        unsigned int v = (unsigned int)f2bf(s[(k0 << 8) + n]) |
                         ((unsigned int)f2bf(s[((k0 + 1) << 8) + n]) << 16);
        int addr = ((mw * 16 + nt) * 8 + kf) * 1024 + lane * 16 + 4 * e;
        *(unsigned int*)(ws + OFF_WPW + addr) = v;
    }
}

// ---------------------------------------------------------------------------
// Dual-bg GRU scan body: ONE block drives TWO batch-groups (bgA = 2*pr,
// bgB = 2*pr+1). Same 16 waves / 4 per SIMD as before (TLP preserved — the
// R7 lesson), but each wave runs two INDEPENDENT recurrence chains that
// share the same register-resident U fragments. The two chains' MFMA/gate
// work interleaves and fills each other's dependency stalls; barriers per
// bg-step halve. WMODE: 1 = wait on MIN of 8 projB flags, 2 = wait on both
// bgs' projA chunk counters == 16. POST: publish pair flag per CHUNK
// (R9 protocol: plain stores, vmcnt drain, wbl2 release fence, flag).
// ---------------------------------------------------------------------------
template <int SCORE, int WMODE, int POST>
__device__ __forceinline__ void scan_pair_body(
    const unsigned int* __restrict__ xp, const unsigned char* __restrict__ wpU,
    int lbase, int pr, unsigned short* __restrict__ hnout,
    const int* __restrict__ xlen, const float* __restrict__ xlab,
    const float* __restrict__ Wo, float* __restrict__ out,
    int* wflags, int* pflag,
    unsigned char (*s1qA)[AST], unsigned char (*s1qB)[AST],
    unsigned char (*rsqA)[AST], unsigned char (*rsqB)[AST],
    float (*s1oA)[264], float (*s1oB)[264],
    float* wo1s, int* s_rdy, int tmax)
{
    const int tid = threadIdx.x, wave = tid >> 6, lane = tid & 63;
    const int l15 = lane & 15, quad = lane >> 4;
    const int bgA = 2 * pr, bgB = 2 * pr + 1;
    const int b0A = bgA * 16, b0B = bgB * 16;

    for (int i = tid; i < 16 * AST; i += 1024) {
        ((unsigned char*)s1qA)[i] = 0;
        ((unsigned char*)s1qB)[i] = 0;
    }
    if (SCORE && tid < DIM) wo1s[tid] = Wo[2 * tid + 1];
    // SCORE bookkeeping: wave 0 -> bgA rows, wave 1 -> bgB rows
    int lenr = 0; float labr = 0.f;
    if (SCORE && wave < 2) {
        lenr = xlen[pr * 32 + wave * 16 + l15];
        labr = xlab[pr * 32 + wave * 16 + l15];
    }

    const int nt = wave;
    const int colA = nt * 16 + l15, rowb = quad * 4;

    // register-resident U fragments — SHARED by both bgs (same layer weights)
    long uz[8], ur[8], uh[8];
    {
        const unsigned char* pz = wpU + (size_t)(((lbase + 0) * 16 + nt) * 4) * 1024 + lane * 16;
        const unsigned char* prg = wpU + (size_t)(((lbase + 1) * 16 + nt) * 4) * 1024 + lane * 16;
        const unsigned char* ph = wpU + (size_t)(((lbase + 2) * 16 + nt) * 4) * 1024 + lane * 16;
#pragma unroll
        for (int kf = 0; kf < 8; ++kf) {
            int o = (kf >> 1) * 1024 + (kf & 1) * 8;
            uz[kf] = *(const long*)(pz + o);
            ur[kf] = *(const long*)(prg + o);
            uh[kf] = *(const long*)(ph + o);
        }
    }
    float s1A[4] = {}, s1B[4] = {};
    float accl = 0.f;
    int ready = 0;
    __syncthreads();

    for (int t = 0; t < tmax; ++t) {
        if constexpr (WMODE == 1) {
            if (t >= ready) {
                if (tid == 0) {
                    int vv, g = 0;
                    for (;;) {
                        vv = 1 << 30;
#pragma unroll
                        for (int q = 0; q < 8; ++q) {
                            int m = __hip_atomic_load(wflags + q, __ATOMIC_RELAXED, __HIP_MEMORY_SCOPE_AGENT);
                            vv = m < vv ? m : vv;
                        }
                        if (vv > t || ++g > (1 << 19)) break;   // fail visibly, never hang
                        __builtin_amdgcn_s_sleep(2);
                    }
                    __threadfence();          // agent acquire before data reads
                    *s_rdy = vv > t ? vv : t + 1;
                }
                __syncthreads();
                ready = *s_rdy;
            }
        } else if constexpr (WMODE == 2) {
            if (t >= ready) {
                if (tid == 0) {
                    const int ch = t >> 4;    // CHUNK == 16
                    int g = 0;
                    for (;;) {
                        int c0 = __hip_atomic_load(wflags + ch,      __ATOMIC_RELAXED, __HIP_MEMORY_SCOPE_AGENT);
                        int c1 = __hip_atomic_load(wflags + 32 + ch, __ATOMIC_RELAXED, __HIP_MEMORY_SCOPE_AGENT);
                        if ((c0 >= 16 && c1 >= 16) || ++g > (1 << 19)) break;  // fail visibly
                        __builtin_amdgcn_s_sleep(2);
                    }
                    __threadfence();          // agent acquire: inv before XP reads
                    *s_rdy = (ch + 1) * CHUNK;
                }
                __syncthreads();
                ready = *s_rdy;
            }
        }

        const unsigned int* xptA = xp + (size_t)(bgA * 512 + t) * 3072 + lane;
        const unsigned int* xptB = xp + (size_t)(bgB * 512 + t) * 3072 + lane;
        unsigned int xzA = xptA[nt * 64],        xzB = xptB[nt * 64];
        unsigned int xrA = xptA[1024 + nt * 64], xrB = xptB[1024 + nt * 64];
        unsigned int xhA = xptA[2048 + nt * 64], xhB = xptB[2048 + nt * 64];

        // ---- phase 1: r + z MFMAs, 4 independent chains interleaved ----
        long sfA[8], sfB[8];
#pragma unroll
        for (int kf = 0; kf < 8; ++kf) {
            sfA[kf] = *(const long*)&s1qA[l15][kf * 32 + quad * 8];
            sfB[kf] = *(const long*)&s1qB[l15][kf * 32 + quad * 8];
        }
        floatx4 zer = {0.f, 0.f, 0.f, 0.f};
        floatx4 raA = zer, raB = zer, zaA = zer, zaB = zer;
#pragma unroll
        for (int kf = 0; kf < 8; ++kf) {
            raA = MFMA_FP8(sfA[kf], ur[kf], raA, 0, 0, 0);
            raB = MFMA_FP8(sfB[kf], ur[kf], raB, 0, 0, 0);
            zaA = MFMA_FP8(sfA[kf], uz[kf], zaA, 0, 0, 0);
            zaB = MFMA_FP8(sfB[kf], uz[kf], zaB, 0, 0, 0);
        }
        float xrfA[4], xrfB[4];
        unp4(xrA, xrfA); unp4(xrB, xrfB);
#pragma unroll
        for (int i = 0; i < 4; ++i) {
            float rA = sigf(0.125f * raA[i] + 0.0625f * xrfA[i]);
            float rB = sigf(0.125f * raB[i] + 0.0625f * xrfB[i]);
            rsqA[rowb + i][colA] = f2q(rA * s1A[i]);
            rsqB[rowb + i][colA] = f2q(rB * s1B[i]);
        }
        BAR_LDS();   // LDS-only: XP loads / HN stores stay in flight

        // ---- phase 2: h MFMAs (2 chains); z-sigmoids overlap ----
        long rfA[8], rfB[8];
#pragma unroll
        for (int kf = 0; kf < 8; ++kf) {
            rfA[kf] = *(const long*)&rsqA[l15][kf * 32 + quad * 8];
            rfB[kf] = *(const long*)&rsqB[l15][kf * 32 + quad * 8];
        }
        floatx4 haA = zer, haB = zer;
#pragma unroll
        for (int kf = 0; kf < 8; ++kf) {
            haA = MFMA_FP8(rfA[kf], uh[kf], haA, 0, 0, 0);
            haB = MFMA_FP8(rfB[kf], uh[kf], haB, 0, 0, 0);
        }
        float xzfA[4], xzfB[4], xhfA[4], xhfB[4];
        unp4(xzA, xzfA); unp4(xzB, xzfB); unp4(xhA, xhfA); unp4(xhB, xhfB);
#pragma unroll
        for (int i = 0; i < 4; ++i) {
            float zA = sigf(0.125f * zaA[i] + 0.0625f * xzfA[i]);
            float hA = tanhfast2y(0.25f * haA[i] + 0.125f * xhfA[i]);
            float hnA = (1.f - zA) * s1A[i] + zA * hA;
            s1A[i] = hnA;
            s1qA[rowb + i][colA] = f2q(hnA);
            s1oA[rowb + i][colA] = hnA;
            float zB = sigf(0.125f * zaB[i] + 0.0625f * xzfB[i]);
            float hB = tanhfast2y(0.25f * haB[i] + 0.125f * xhfB[i]);
            float hnB = (1.f - zB) * s1B[i] + zB * hB;
            s1B[i] = hnB;
            s1qB[rowb + i][colA] = f2q(hnB);
            s1oB[rowb + i][colA] = hnB;
        }
        BAR_LDS();   // LDS-only

        if (!SCORE) {
            // cooperative hn0 writes for both bgs; coalesced 8B stores
            const int r = tid >> 6, c = (tid & 63) * 4;
            float4 fa = *(const float4*)&s1oA[r][c];
            float4 fb = *(const float4*)&s1oB[r][c];
            uint2 oa, ob;
            oa.x = f2bf(fa.x) | ((unsigned)f2bf(fa.y) << 16);
            oa.y = f2bf(fa.z) | ((unsigned)f2bf(fa.w) << 16);
            ob.x = f2bf(fb.x) | ((unsigned)f2bf(fb.y) << 16);
            ob.y = f2bf(fb.z) | ((unsigned)f2bf(fb.w) << 16);
            *(uint2*)(hnout + ((size_t)(b0A + r) * 512 + t) * 256 + c) = oa;
            *(uint2*)(hnout + ((size_t)(b0B + r) * 512 + t) * 256 + c) = ob;
        } else if (wave < 2) {
            // wave 0 scores bgA rows, wave 1 scores bgB rows
            const float* so = (wave == 0) ? &s1oA[0][0] : &s1oB[0][0];
            const int row = l15, c0 = quad * 64;
            float p = 0.f;
#pragma unroll
            for (int u = 0; u < 64; u += 4) {
                float4 sv = *(const float4*)(so + row * 264 + c0 + u);
                float4 wv = *(const float4*)&wo1s[c0 + u];
                p = fmaf(sv.x, wv.x, p); p = fmaf(sv.y, wv.y, p);
                p = fmaf(sv.z, wv.z, p); p = fmaf(sv.w, wv.w, p);
            }
            p += __shfl_xor(p, 16);
            p += __shfl_xor(p, 32);
            if (lane < 16 && t < lenr) {
                float sc = sigf(p);
                float d = labr - sc;
                accl = fmaf(d, d, accl);
            }
        }

        if (POST && (((t & (CHUNK - 1)) == (CHUNK - 1)) || t == tmax - 1)) {
            __syncthreads();   // FULL drain: all waves' HN stores (vmcnt0) before fence
            if (tid == 0) {
                __threadfence();   // agent release: push chunk data to coherent point
                __hip_atomic_store(pflag, t + 1, __ATOMIC_RELEASE, __HIP_MEMORY_SCOPE_AGENT);
            }
        }
    }

    if (SCORE && wave < 2) {
        accl += __shfl_xor(accl, 1);
        accl += __shfl_xor(accl, 2);
        accl += __shfl_xor(accl, 4);
        accl += __shfl_xor(accl, 8);
        if (lane == 0) atomicAdd(out, accl);
    }
}

// ---------------------------------------------------------------------------
// Fused pipeline + in-grid projA, 2068 WGs:
//   blocks 0-1   : layer-0 dual-bg scans (pair pr; waits both bgs' projA
//                  counters == 16 per chunk; posts flags[pr])
//   blocks 2-17  : projB, 4 WGs per bg; waits flags[bg>>1], posts
//                  flags[4+bg*4+p] (R9 release protocol)
//   blocks 18-19 : layer-1 dual-bg scans + loss (waits MIN of pair's 8
//                  projB flags)
//   blocks 20-2067: projA, one (bg,t) each; agent-scope XP stores + counter
//                  (cheap-producer protocol, validated R9)
// ---------------------------------------------------------------------------
__global__ __launch_bounds__(1024, 4) void fused_pipeline(
    const float* __restrict__ x,
    unsigned int* __restrict__ XP, unsigned int* __restrict__ HP,
    const unsigned char* __restrict__ wpU, const unsigned char* __restrict__ wpW,
    unsigned short* __restrict__ HN,
    const int* __restrict__ xlen, const float* __restrict__ xlab,
    const float* __restrict__ Wo, float* __restrict__ out, int* flags)
{
    __shared__ __align__(16) unsigned char s1qA[16][AST];
    __shared__ __align__(16) unsigned char s1qB[16][AST];
    __shared__ __align__(16) unsigned char rsqA[16][AST];
    __shared__ __align__(16) unsigned char rsqB[16][AST];
    __shared__ __align__(16) float s1oA[16][264];
    __shared__ __align__(16) float s1oB[16][264];
    __shared__ float wo1s[DIM];
    __shared__ int s_rdy;

    const int bid = blockIdx.x;
    const int tid = threadIdx.x, wave = tid >> 6, lane = tid & 63;
    const int l15 = lane & 15, quad = lane >> 4;
    int* cnt = flags + 32;   // projA chunk counters, bg*32+chunk

    if (bid >= 20) {
        // ---- projA: XP[t] = x[t] @ W(l0); one (bg,t) per block ----
        const int idx = bid - 20;            // 0..2047
        const int pt = idx & 511, pbg = idx >> 9;
        const float* s = x + ((size_t)(pbg * 16 + l15) * 512 + pt) * 256;
        bf16x8 af[8];
#pragma unroll
        for (int kf = 0; kf < 8; ++kf) {
            float4 a = *(const float4*)(s + kf * 32 + quad * 8);
            float4 b = *(const float4*)(s + kf * 32 + quad * 8 + 4);
            union { unsigned short u[8]; bf16x8 v; } cv;
            cv.u[0] = f2bf(a.x); cv.u[1] = f2bf(a.y); cv.u[2] = f2bf(a.z); cv.u[3] = f2bf(a.w);
            cv.u[4] = f2bf(b.x); cv.u[5] = f2bf(b.y); cv.u[6] = f2bf(b.z); cv.u[7] = f2bf(b.w);
            af[kf] = cv.v;
        }
        floatx4 az = {0.f, 0.f, 0.f, 0.f}, ar = az, ah = az;
        const unsigned char* bz = wpW + (size_t)((0 * 16 + wave) * 8) * 1024 + lane * 16;
        const unsigned char* br = wpW + (size_t)((1 * 16 + wave) * 8) * 1024 + lane * 16;
        const unsigned char* bh = wpW + (size_t)((2 * 16 + wave) * 8) * 1024 + lane * 16;
#pragma unroll
        for (int kf = 0; kf < 8; ++kf) {
            az = MFMA_BF16(af[kf], *(const bf16x8*)(bz + kf * 1024), az, 0, 0, 0);
            ar = MFMA_BF16(af[kf], *(const bf16x8*)(br + kf * 1024), ar, 0, 0, 0);
            ah = MFMA_BF16(af[kf], *(const bf16x8*)(bh + kf * 1024), ah, 0, 0, 0);
        }
        const size_t ob = (size_t)(pbg * 512 + pt) * 3072 + wave * 64 + lane;
        ast_u32(&XP[ob],        pk2(16.f * az[0], 16.f * az[1]) | (pk2(16.f * az[2], 16.f * az[3]) << 16));
        ast_u32(&XP[ob + 1024], pk2(16.f * ar[0], 16.f * ar[1]) | (pk2(16.f * ar[2], 16.f * ar[3]) << 16));
        ast_u32(&XP[ob + 2048], pk2(16.f * ah[0], 16.f * ah[1]) | (pk2(16.f * ah[2], 16.f * ah[3]) << 16));
        __syncthreads();   // vmcnt(0): all block's coherent stores complete
        if (tid == 0)
            __hip_atomic_fetch_add(cnt + pbg * 32 + (pt >> 4), 1,
                                   __ATOMIC_RELAXED, __HIP_MEMORY_SCOPE_AGENT);
        return;
    }

    int role, pr = 0, bg = 0, p = 0;
    if (bid < 2)       { role = 0; pr = bid; }
    else if (bid < 18) { role = 1; bg = (bid - 2) >> 2; p = (bid - 2) & 3; }
    else               { role = 2; pr = bid - 18; }

    if (role == 0 || role == 2) {
        // uniform tmax = max xlen over the PAIR's 32 rows
        int v = max(xlen[pr * 32 + l15], xlen[pr * 32 + 16 + l15]);
#pragma unroll
        for (int o = 1; o < 16; o <<= 1) v = max(v, __shfl_xor(v, o));
        const int tmax = __builtin_amdgcn_readfirstlane(v);

        if (role == 0) {
            scan_pair_body<0, 2, 1>(XP, wpU, 0, pr, HN, xlen, xlab, Wo, out,
                                    cnt + pr * 64, flags + pr,
                                    s1qA, s1qB, rsqA, rsqB, s1oA, s1oB,
                                    wo1s, &s_rdy, tmax);
        } else {
            scan_pair_body<1, 1, 0>(HP, wpU, 3, pr, nullptr, xlen, xlab, Wo, out,
                                    flags + 4 + pr * 8, nullptr,
                                    s1qA, s1qB, rsqA, rsqB, s1oA, s1oB,
                                    wo1s, &s_rdy, tmax);
        }
        return;
    }

    // ---- projB: HP[t] = HN[t] @ W(l1); this WG owns 4 t per chunk ----
    const int b0 = bg * 16;
    int v = xlen[b0 + l15];
#pragma unroll
    for (int o = 1; o < 16; o <<= 1) v = max(v, __shfl_xor(v, o));
    int tmax = __builtin_amdgcn_readfirstlane(v);
    {   // pair tmax (scan0 runs to the pair max; flag advances to it)
        int v2 = xlen[(bg ^ 1) * 16 + l15];
#pragma unroll
        for (int o = 1; o < 16; o <<= 1) v2 = max(v2, __shfl_xor(v2, o));
        int tm2 = __builtin_amdgcn_readfirstlane(v2);
        tmax = max(tmax, tm2);   // keep flag targets consistent with producer
    }
    int* wf = flags + (bg >> 1);
    int* pf = flags + 4 + bg * 4 + p;
    const unsigned char* bz = wpW + (size_t)(((3 + 0) * 16 + wave) * 8) * 1024 + lane * 16;
    const unsigned char* br = wpW + (size_t)(((3 + 1) * 16 + wave) * 8) * 1024 + lane * 16;
    const unsigned char* bh = wpW + (size_t)(((3 + 2) * 16 + wave) * 8) * 1024 + lane * 16;
    for (int base = 0; base < tmax; base += CHUNK) {
        const int target = (base + CHUNK < tmax) ? base + CHUNK : tmax;
        if (tid == 0) {
            int vv, g = 0;
            for (;;) {
                vv = __hip_atomic_load(wf, __ATOMIC_RELAXED, __HIP_MEMORY_SCOPE_AGENT);
                if (vv >= target || ++g > (1 << 19)) break;
                __builtin_amdgcn_s_sleep(2);
            }
            __threadfence();   // acquire: inv before reading scan0's HN chunk
        }
        __syncthreads();       // no wave reads HN before the inv

        const int t0 = base + p * 4;
        const int t1 = (t0 + 4 < tmax) ? t0 + 4 : tmax;
        for (int t = t0; t < t1; ++t) {
            const unsigned short* sA = HN + ((size_t)(b0 + l15) * 512 + t) * 256;
            bf16x8 af[8];
#pragma unroll
            for (int kf = 0; kf < 8; ++kf) af[kf] = *(const bf16x8*)(sA + kf * 32 + quad * 8);
            floatx4 az = {0.f, 0.f, 0.f, 0.f}, ar = az, ah = az;
#pragma unroll
            for (int kf = 0; kf < 8; ++kf) {
                az = MFMA_BF16(af[kf], *(const bf16x8*)(bz + kf * 1024), az, 0, 0, 0);
                ar = MFMA_BF16(af[kf], *(const bf16x8*)(br + kf * 1024), ar, 0, 0, 0);
                ah = MFMA_BF16(af[kf], *(const bf16x8*)(bh + kf * 1024), ah, 0, 0, 0);
            }
            const size_t ob = (size_t)(bg * 512 + t) * 3072 + wave * 64 + lane;
            HP[ob]        = pk2(16.f * az[0], 16.f * az[1]) | (pk2(16.f * az[2], 16.f * az[3]) << 16);
            HP[ob + 1024] = pk2(16.f * ar[0], 16.f * ar[1]) | (pk2(16.f * ar[2], 16.f * ar[3]) << 16);
            HP[ob + 2048] = pk2(16.f * ah[0], 16.f * ah[1]) | (pk2(16.f * ah[2], 16.f * ah[3]) << 16);
        }

        __syncthreads();   // all waves' HP stores drained (vmcnt0 before barrier)
        if (tid == 0) {
            __threadfence();   // release: push HP chunk to coherent point
            __hip_atomic_store(pf, base + CHUNK, __ATOMIC_RELEASE, __HIP_MEMORY_SCOPE_AGENT);
        }
    }
}

extern "C" void kernel_launch(void* const* d_in, const int* in_sizes, int n_in,
                              void* d_out, int out_size, void* d_ws, size_t ws_size,
                              hipStream_t stream) {
    const float* x    = (const float*)d_in[0];
    const int*   xlen = (const int*)d_in[1];
    const float* xlab = (const float*)d_in[2];
    const float* Wz   = (const float*)d_in[3];
    const float* Uz   = (const float*)d_in[4];
    const float* Wr   = (const float*)d_in[5];
    const float* Ur   = (const float*)d_in[6];
    const float* Wh   = (const float*)d_in[7];
    const float* Uh   = (const float*)d_in[8];
    const float* Wo   = (const float*)d_in[9];
    float* out = (float*)d_out;

    unsigned char* ws  = (unsigned char*)d_ws;
    unsigned char* wpU = ws;                                 // fp8 U-frags, 384 KB
    unsigned char* wpW = ws + OFF_WPW;                       // bf16 W-frags, 768 KB
    int*           FLG = (int*)(ws + OFF_FLG);               // flags + counters
    unsigned int*  XP  = (unsigned int*)(ws + OFF_XP);       // 25.2 MB
    unsigned int*  HP  = (unsigned int*)(ws + OFF_HP);       // 25.2 MB
    unsigned short* HN = (unsigned short*)(ws + OFF_HN);     // 16.8 MB

    // ws re-poisoned every call -> rebuild everything (incl. flags) each time.
    prep_weights<<<1536, 256, 0, stream>>>(Wz, Wr, Wh, Uz, Ur, Uh, ws, out);
    fused_pipeline<<<2068, 1024, 0, stream>>>(x, XP, HP, wpU, wpW, HN,
                                              xlen, xlab, Wo, out, FLG);
}

// Round 12
// 1233.020 us; speedup vs baseline: 1.7677x; 1.7677x over previous
//
#include <hip/hip_runtime.h>

// Dims fixed by the reference
#define LAY 2
#define BATCH 64
#define TMAX 512
#define DIM 256
#define AST 264    // LDS activation row stride (bytes, fp8)
#define CHUNK 16   // pipeline handoff granularity (timesteps)

typedef float floatx4 __attribute__((ext_vector_type(4)));
typedef __bf16 bf16x8 __attribute__((ext_vector_type(8)));
#define MFMA_FP8  __builtin_amdgcn_mfma_f32_16x16x32_fp8_fp8
#define MFMA_BF16 __builtin_amdgcn_mfma_f32_16x16x32_bf16

// LDS-only barrier: orders ds ops (lgkmcnt) without draining vmcnt.
#define BAR_LDS() asm volatile("s_waitcnt lgkmcnt(0)\n\ts_barrier" ::: "memory")

// d_ws layout (requires ws >= ~74 MB)
// wpU: 9 fp8 mats (6 U + 3 W(l1)), 9 x 64 KB = 576 KB (ends 0x90000)
#define OFF_WPW 0xA0000     // bf16 B-frag W(l0) mats, 3 x 128 KB (ends 0x100000)
#define OFF_FLG 0x150000    // [0..3] scan0 flags, [4..19] projB flags,
                            // [32..159] projA chunk counters (bg*32+chunk)
#define OFF_XP  0x200000    // layer-0 X-projections fp8, 25.2 MB
#define OFF_HP  0x1C00000   // layer-1 input projections fp8, 25.2 MB
#define OFF_HN  0x3600000   // hn0 fp8 [b*512+t][256], 8.4 MB

__device__ __forceinline__ unsigned short f2bf(float f) {
    unsigned int u = __float_as_uint(f);
    unsigned int r = u + 0x7fffu + ((u >> 16) & 1u);  // RNE
    return (unsigned short)(r >> 16);
}
__device__ __forceinline__ unsigned int pk2(float a, float b) {
    return (unsigned int)__builtin_amdgcn_cvt_pk_fp8_f32(a, b, 0, false);  // OCP e4m3 x2
}
__device__ __forceinline__ unsigned char f2q(float a) { return (unsigned char)(pk2(a, a) & 0xff); }
__device__ __forceinline__ void unp4(unsigned int u, float* f) {
    auto lo = __builtin_amdgcn_cvt_pk_f32_fp8((int)u, false);
    auto hi = __builtin_amdgcn_cvt_pk_f32_fp8((int)u, true);
    f[0] = lo[0]; f[1] = lo[1]; f[2] = hi[0]; f[3] = hi[1];
}
// sigmoid via raw v_rcp_f32 (1 instr vs ~10-instr IEEE div sequence).
__device__ __forceinline__ float sigf(float x) {
    return __builtin_amdgcn_rcpf(1.f + __expf(-x));
}
// tanh(y) = 2*sigmoid(2y) - 1
__device__ __forceinline__ float tanhfast2y(float twoy) { return 2.f * sigf(twoy) - 1.f; }

// agent-scope relaxed store: device-coherent at the LLC (projA XP path only —
// R10 showed write-through costs +14MB HBM when applied to HN/HP, so those
// edges keep the R9 wbl2-release protocol)
__device__ __forceinline__ void ast_u32(unsigned int* p, unsigned int v) {
    __hip_atomic_store(p, v, __ATOMIC_RELAXED, __HIP_MEMORY_SCOPE_AGENT);
}

// ---------------------------------------------------------------------------
// Weight prep. fp8 section now 9 mats (mu 0..5 = U layer0/1, mu 6..8 =
// W(l1) z/r/h — projB runs fp8 x fp8). bf16 section: W(l0) only (projA's
// A comes from f32 x, keep that link bf16). Zeroes flags+counters + d_out.
// ---------------------------------------------------------------------------
__global__ void prep_weights(const float* __restrict__ Wz, const float* __restrict__ Wr,
                             const float* __restrict__ Wh, const float* __restrict__ Uz,
                             const float* __restrict__ Ur, const float* __restrict__ Uh,
                             unsigned char* __restrict__ ws, float* __restrict__ out) {
    int T = blockIdx.x * 256 + threadIdx.x;  // 1536*256 = 393216
    if (T == 0) out[0] = 0.f;
    if (T < 192) ((int*)(ws + OFF_FLG))[T] = 0;  // flags + projA counters
    if (T < 294912) {  // fp8 mats: 9 x 32768 threads
        int e = T & 3, half = (T >> 2) & 1, lane = (T >> 3) & 63;
        int kp = (T >> 9) & 3, nt = (T >> 11) & 15, mu = T >> 15;
        const float* s;
        if (mu < 6) {
            int g = mu % 3, l = mu / 3;
            s = (g == 0 ? Uz : g == 1 ? Ur : Uh) + l * 65536;
        } else {
            int g = mu - 6;                       // W(l1) fp8 for projB
            s = (g == 0 ? Wz : g == 1 ? Wr : Wh) + 65536;
        }
        int n  = nt * 16 + (lane & 15);
        int k0 = (2 * kp + half) * 32 + (lane >> 4) * 8 + 2 * e;
        float w0 = s[(k0 << 8) + n] * 8.f;        // x8: dodge e4m3 denormals
        float w1 = s[((k0 + 1) << 8) + n] * 8.f;  // undone by 0.125 post-acc
        int addr = ((mu * 16 + nt) * 4 + kp) * 1024 + lane * 16 + half * 8 + 2 * e;
        *(unsigned short*)(ws + addr) = (unsigned short)(pk2(w0, w1) & 0xffff);
    } else {           // W(l0) bf16: 3 x 32768 threads
        int T2 = T - 294912;
        int e = T2 & 3, lane = (T2 >> 2) & 63;
        int kf = (T2 >> 8) & 7, nt = (T2 >> 11) & 15, mw = T2 >> 15;
        const float* s = (mw == 0 ? Wz : mw == 1 ? Wr : Wh);   // layer 0
        int n  = nt * 16 + (lane & 15);
        int k0 = kf * 32 + (lane >> 4) * 8 + 2 * e;
        unsigned int v = (unsigned int)f2bf(s[(k0 << 8) + n]) |
                         ((unsigned int)f2bf(s[((k0 + 1) << 8) + n]) << 16);
        int addr = ((mw * 16 + nt) * 8 + kf) * 1024 + lane * 16 + 4 * e;
        *(unsigned int*)(ws + OFF_WPW + addr) = v;
    }
}

// ---------------------------------------------------------------------------
// GRU scan body (R9 structure, 16 waves x 1 col-tile). WMODE: 1 = wait on
// MIN of 4 projB flags, 2 = wait on projA chunk counter == 16. POST: publish
// pflag per CHUNK (R9 protocol: plain HN stores, vmcnt drain at the
// __syncthreads, wbl2 release fence, flag). HN is fp8: the cooperative
// writer re-uses s1q's bytes directly (no f2bf, no s1o round-trip); s1o is
// only written on the SCORE path.
// ---------------------------------------------------------------------------
template <int SCORE, int WMODE, int POST>
__device__ __forceinline__ void scan_body(
    const unsigned int* __restrict__ xp, const unsigned char* __restrict__ wpU,
    int lbase, int bg, unsigned char* __restrict__ hnout,
    const int* __restrict__ xlen, const float* __restrict__ xlab,
    const float* __restrict__ Wo, float* __restrict__ out,
    int* wflags, int* pflag,
    unsigned char (*s1q)[AST], unsigned char (*rsq)[AST], float (*s1o)[264],
    float* wo1s, int* s_rdy, int tmax)
{
    const int tid = threadIdx.x, wave = tid >> 6, lane = tid & 63;
    const int l15 = lane & 15, quad = lane >> 4;
    const int b0 = bg * 16;

    for (int i = tid; i < 16 * AST; i += 1024) ((unsigned char*)s1q)[i] = 0;
    if (SCORE && tid < DIM) wo1s[tid] = Wo[2 * tid + 1];
    const int lenr = xlen[b0 + l15];
    const float labr = SCORE ? xlab[b0 + l15] : 0.f;
    (void)lenr; (void)labr;

    const int nt = wave;
    const int colA = nt * 16 + l15, rowb = quad * 4;

    // register-resident U fragments for this wave's 16-col tile
    long uz[8], ur[8], uh[8];
    {
        const unsigned char* pz = wpU + (size_t)(((lbase + 0) * 16 + nt) * 4) * 1024 + lane * 16;
        const unsigned char* pr = wpU + (size_t)(((lbase + 1) * 16 + nt) * 4) * 1024 + lane * 16;
        const unsigned char* ph = wpU + (size_t)(((lbase + 2) * 16 + nt) * 4) * 1024 + lane * 16;
#pragma unroll
        for (int kf = 0; kf < 8; ++kf) {
            int o = (kf >> 1) * 1024 + (kf & 1) * 8;
            uz[kf] = *(const long*)(pz + o);
            ur[kf] = *(const long*)(pr + o);
            uh[kf] = *(const long*)(ph + o);
        }
    }
    float s1r[4] = {};
    float accl = 0.f;
    int ready = 0;
    __syncthreads();

    for (int t = 0; t < tmax; ++t) {
        if constexpr (WMODE == 1) {
            if (t >= ready) {
                if (tid == 0) {
                    int vv, g = 0;
                    for (;;) {
                        vv = 1 << 30;
#pragma unroll
                        for (int q = 0; q < 4; ++q) {
                            int m = __hip_atomic_load(wflags + q, __ATOMIC_RELAXED, __HIP_MEMORY_SCOPE_AGENT);
                            vv = m < vv ? m : vv;
                        }
                        if (vv > t || ++g > (1 << 19)) break;   // fail visibly, never hang
                        __builtin_amdgcn_s_sleep(2);
                    }
                    __threadfence();          // agent acquire before data reads
                    *s_rdy = vv > t ? vv : t + 1;
                }
                __syncthreads();
                ready = *s_rdy;
            }
        } else if constexpr (WMODE == 2) {
            if (t >= ready) {
                if (tid == 0) {
                    const int ch = t >> 4;    // CHUNK == 16
                    int g = 0;
                    for (;;) {
                        int c = __hip_atomic_load(wflags + ch, __ATOMIC_RELAXED, __HIP_MEMORY_SCOPE_AGENT);
                        if (c >= 16 || ++g > (1 << 19)) break;  // fail visibly, never hang
                        __builtin_amdgcn_s_sleep(2);
                    }
                    __threadfence();          // agent acquire: inv before XP reads
                    *s_rdy = (ch + 1) * CHUNK;
                }
                __syncthreads();
                ready = *s_rdy;
            }
        }

        const unsigned int* xpt = xp + (size_t)(bg * 512 + t) * 3072 + lane;
        unsigned int xz = xpt[nt * 64];
        unsigned int xr = xpt[1024 + nt * 64];
        unsigned int xh = xpt[2048 + nt * 64];

        // ---- phase 1: r (on the critical path) + z-MFMAs (acc dangles) ----
        long sf[8];
#pragma unroll
        for (int kf = 0; kf < 8; ++kf) sf[kf] = *(const long*)&s1q[l15][kf * 32 + quad * 8];
        floatx4 za = {0.f, 0.f, 0.f, 0.f}, ra = za;
#pragma unroll
        for (int kf = 0; kf < 8; ++kf) {
            ra = MFMA_FP8(sf[kf], ur[kf], ra, 0, 0, 0);
            za = MFMA_FP8(sf[kf], uz[kf], za, 0, 0, 0);
        }
        float xrf[4];
        unp4(xr, xrf);
#pragma unroll
        for (int i = 0; i < 4; ++i) {
            float r = sigf(0.125f * ra[i] + 0.0625f * xrf[i]);
            rsq[rowb + i][colA] = f2q(r * s1r[i]);
        }
        BAR_LDS();   // LDS-only: XP loads / HN stores stay in flight

        // ---- phase 2: h; z-sigmoid overlaps the Uh MFMA ----
        long rf[8];
#pragma unroll
        for (int kf = 0; kf < 8; ++kf) rf[kf] = *(const long*)&rsq[l15][kf * 32 + quad * 8];
        floatx4 ha = {0.f, 0.f, 0.f, 0.f};
#pragma unroll
        for (int kf = 0; kf < 8; ++kf) ha = MFMA_FP8(rf[kf], uh[kf], ha, 0, 0, 0);
        float xzf[4], xhf[4];
        unp4(xz, xzf); unp4(xh, xhf);
#pragma unroll
        for (int i = 0; i < 4; ++i) {
            float z = sigf(0.125f * za[i] + 0.0625f * xzf[i]);
            float h = tanhfast2y(0.25f * ha[i] + 0.125f * xhf[i]);  // tanh(0.125ha+0.0625xh)
            float hn = (1.f - z) * s1r[i] + z * h;
            s1r[i] = hn;
            s1q[rowb + i][colA] = f2q(hn);
            if (SCORE) s1o[rowb + i][colA] = hn;   // f32 copy only for scoring
        }
        BAR_LDS();   // LDS-only

        if (!SCORE) {
            // hn0 write, fp8: re-use s1q's bytes (what the recurrence itself
            // consumes) — no f2bf, 4B/thread, coalesced 256B/wave
            const int r = tid >> 6, c = (tid & 63) * 4;
            unsigned int v4 = *(const unsigned int*)&s1q[r][c];
            *(unsigned int*)(hnout + ((size_t)(b0 + r) * 512 + t) * 256 + c) = v4;
        } else if (wave == 0) {
            const int row = l15, c0 = quad * 64;
            float p = 0.f;
#pragma unroll
            for (int u = 0; u < 64; u += 4) {
                float4 sv = *(const float4*)&s1o[row][c0 + u];
                float4 wv = *(const float4*)&wo1s[c0 + u];
                p = fmaf(sv.x, wv.x, p); p = fmaf(sv.y, wv.y, p);
                p = fmaf(sv.z, wv.z, p); p = fmaf(sv.w, wv.w, p);
            }
            p += __shfl_xor(p, 16);
            p += __shfl_xor(p, 32);
            if (lane < 16 && t < lenr) {
                float sc = sigf(p);
                float d = labr - sc;
                accl = fmaf(d, d, accl);
            }
        }

        if (POST && (((t & (CHUNK - 1)) == (CHUNK - 1)) || t == tmax - 1)) {
            __syncthreads();   // FULL drain: all waves' HN stores (vmcnt0) before fence
            if (tid == 0) {
                __threadfence();   // agent release: push chunk data to coherent point
                __hip_atomic_store(pflag, t + 1, __ATOMIC_RELEASE, __HIP_MEMORY_SCOPE_AGENT);
            }
        }
    }

    if (SCORE && wave == 0) {
        accl += __shfl_xor(accl, 1);
        accl += __shfl_xor(accl, 2);
        accl += __shfl_xor(accl, 4);
        accl += __shfl_xor(accl, 8);
        if (lane == 0) atomicAdd(out, accl);
    }
}

// ---------------------------------------------------------------------------
// Fused pipeline + in-grid projA, 2072 WGs (R9 topology):
//   blocks 0-3   : layer-0 scan (waits projA counter==16 per chunk;
//                  posts flags[bg] per chunk; writes HN fp8)
//   blocks 4-19  : projB, 4 WGs per bg; waits flags[bg], posts flags[4+bg*4+p]
//                  — now fp8 A (HN) x fp8 B (W(l1) x8-scaled), out pk2(2*acc)
//   blocks 20-23 : layer-1 scan + loss (waits MIN of the bg's 4 projB flags)
//   blocks 24-2071: projA, one (bg,t) each; agent-scope XP stores + counter
// ---------------------------------------------------------------------------
__global__ __launch_bounds__(1024, 4) void fused_pipeline(
    const float* __restrict__ x,
    unsigned int* __restrict__ XP, unsigned int* __restrict__ HP,
    const unsigned char* __restrict__ wpU, const unsigned char* __restrict__ wpW,
    unsigned char* __restrict__ HN,
    const int* __restrict__ xlen, const float* __restrict__ xlab,
    const float* __restrict__ Wo, float* __restrict__ out, int* flags)
{
    __shared__ __align__(16) unsigned char s1q[16][AST];
    __shared__ __align__(16) unsigned char rsq[16][AST];
    __shared__ __align__(16) float s1o[16][264];
    __shared__ float wo1s[DIM];
    __shared__ int s_rdy;

    const int bid = blockIdx.x;
    const int tid = threadIdx.x, wave = tid >> 6, lane = tid & 63;
    const int l15 = lane & 15, quad = lane >> 4;
    int* cnt = flags + 32;   // projA chunk counters, bg*32+chunk

    if (bid >= 24) {
        // ---- projA: XP[t] = x[t] @ W(l0); one (bg,t) per block ----
        const int idx = bid - 24;            // 0..2047
        const int pt = idx & 511, pbg = idx >> 9;
        const float* s = x + ((size_t)(pbg * 16 + l15) * 512 + pt) * 256;
        bf16x8 af[8];
#pragma unroll
        for (int kf = 0; kf < 8; ++kf) {
            float4 a = *(const float4*)(s + kf * 32 + quad * 8);
            float4 b = *(const float4*)(s + kf * 32 + quad * 8 + 4);
            union { unsigned short u[8]; bf16x8 v; } cv;
            cv.u[0] = f2bf(a.x); cv.u[1] = f2bf(a.y); cv.u[2] = f2bf(a.z); cv.u[3] = f2bf(a.w);
            cv.u[4] = f2bf(b.x); cv.u[5] = f2bf(b.y); cv.u[6] = f2bf(b.z); cv.u[7] = f2bf(b.w);
            af[kf] = cv.v;
        }
        floatx4 az = {0.f, 0.f, 0.f, 0.f}, ar = az, ah = az;
        const unsigned char* bz = wpW + (size_t)((0 * 16 + wave) * 8) * 1024 + lane * 16;
        const unsigned char* br = wpW + (size_t)((1 * 16 + wave) * 8) * 1024 + lane * 16;
        const unsigned char* bh = wpW + (size_t)((2 * 16 + wave) * 8) * 1024 + lane * 16;
#pragma unroll
        for (int kf = 0; kf < 8; ++kf) {
            az = MFMA_BF16(af[kf], *(const bf16x8*)(bz + kf * 1024), az, 0, 0, 0);
            ar = MFMA_BF16(af[kf], *(const bf16x8*)(br + kf * 1024), ar, 0, 0, 0);
            ah = MFMA_BF16(af[kf], *(const bf16x8*)(bh + kf * 1024), ah, 0, 0, 0);
        }
        const size_t ob = (size_t)(pbg * 512 + pt) * 3072 + wave * 64 + lane;
        ast_u32(&XP[ob],        pk2(16.f * az[0], 16.f * az[1]) | (pk2(16.f * az[2], 16.f * az[3]) << 16));
        ast_u32(&XP[ob + 1024], pk2(16.f * ar[0], 16.f * ar[1]) | (pk2(16.f * ar[2], 16.f * ar[3]) << 16));
        ast_u32(&XP[ob + 2048], pk2(16.f * ah[0], 16.f * ah[1]) | (pk2(16.f * ah[2], 16.f * ah[3]) << 16));
        __syncthreads();   // vmcnt(0): all block's coherent stores complete
        if (tid == 0)
            __hip_atomic_fetch_add(cnt + pbg * 32 + (pt >> 4), 1,
                                   __ATOMIC_RELAXED, __HIP_MEMORY_SCOPE_AGENT);
        return;
    }

    int role, bg, p = 0;
    if (bid < 4)       { role = 0; bg = bid; }
    else if (bid < 20) { role = 1; bg = (bid - 4) >> 2; p = (bid - 4) & 3; }
    else               { role = 2; bg = bid - 20; }
    const int b0 = bg * 16;

    // uniform tmax = max xlen over this bg's 16 rows (same in all stages)
    int v = xlen[b0 + l15];
#pragma unroll
    for (int o = 1; o < 16; o <<= 1) v = max(v, __shfl_xor(v, o));
    const int tmax = __builtin_amdgcn_readfirstlane(v);

    if (role == 0) {
        scan_body<0, 2, 1>(XP, wpU, 0, bg, HN, xlen, xlab, Wo, out,
                           cnt + bg * 32, flags + bg, s1q, rsq, s1o, wo1s, &s_rdy, tmax);
    } else if (role == 2) {
        scan_body<1, 1, 0>(HP, wpU, 3, bg, nullptr, xlen, xlab, Wo, out,
                           flags + 4 + bg * 4, nullptr, s1q, rsq, s1o, wo1s, &s_rdy, tmax);
    } else {
        // ---- projB: HP[t] = HN[t] @ W(l1), fp8 x fp8; 4 t per chunk ----
        int* wf = flags + bg;
        int* pf = flags + 4 + bg * 4 + p;
        // fp8 B-frags: mats 6/7/8 in the wpU region (x8-scaled)
        const unsigned char* bz = wpU + (size_t)((6 * 16 + wave) * 4) * 1024 + lane * 16;
        const unsigned char* br = wpU + (size_t)((7 * 16 + wave) * 4) * 1024 + lane * 16;
        const unsigned char* bh = wpU + (size_t)((8 * 16 + wave) * 4) * 1024 + lane * 16;
        for (int base = 0; base < tmax; base += CHUNK) {
            const int target = (base + CHUNK < tmax) ? base + CHUNK : tmax;
            if (tid == 0) {
                int vv, g = 0;
                for (;;) {
                    vv = __hip_atomic_load(wf, __ATOMIC_RELAXED, __HIP_MEMORY_SCOPE_AGENT);
                    if (vv >= target || ++g > (1 << 19)) break;
                    __builtin_amdgcn_s_sleep(2);
                }
                __threadfence();   // acquire: inv before reading scan0's HN chunk
            }
            __syncthreads();       // no wave reads HN before the inv

            const int t0 = base + p * 4;
            const int t1 = (t0 + 4 < tmax) ? t0 + 4 : tmax;
            for (int t = t0; t < t1; ++t) {
                const unsigned char* sA = HN + ((size_t)(b0 + l15) * 512 + t) * 256;
                long af[8];
#pragma unroll
                for (int kf = 0; kf < 8; ++kf) af[kf] = *(const long*)(sA + kf * 32 + quad * 8);
                floatx4 az = {0.f, 0.f, 0.f, 0.f}, ar = az, ah = az;
#pragma unroll
                for (int kf = 0; kf < 8; ++kf) {
                    int o = (kf >> 1) * 1024 + (kf & 1) * 8;
                    az = MFMA_FP8(af[kf], *(const long*)(bz + o), az, 0, 0, 0);
                    ar = MFMA_FP8(af[kf], *(const long*)(br + o), ar, 0, 0, 0);
                    ah = MFMA_FP8(af[kf], *(const long*)(bh + o), ah, 0, 0, 0);
                }
                // acc = hn * (8W) -> want pk2(16 * hn*W) = pk2(2 * acc)
                const size_t ob = (size_t)(bg * 512 + t) * 3072 + wave * 64 + lane;
                HP[ob]        = pk2(2.f * az[0], 2.f * az[1]) | (pk2(2.f * az[2], 2.f * az[3]) << 16);
                HP[ob + 1024] = pk2(2.f * ar[0], 2.f * ar[1]) | (pk2(2.f * ar[2], 2.f * ar[3]) << 16);
                HP[ob + 2048] = pk2(2.f * ah[0], 2.f * ah[1]) | (pk2(2.f * ah[2], 2.f * ah[3]) << 16);
            }

            __syncthreads();   // all waves' HP stores drained (vmcnt0 before barrier)
            if (tid == 0) {
                __threadfence();   // release: push HP chunk to coherent point
                __hip_atomic_store(pf, base + CHUNK, __ATOMIC_RELEASE, __HIP_MEMORY_SCOPE_AGENT);
            }
        }
    }
}

extern "C" void kernel_launch(void* const* d_in, const int* in_sizes, int n_in,
                              void* d_out, int out_size, void* d_ws, size_t ws_size,
                              hipStream_t stream) {
    const float* x    = (const float*)d_in[0];
    const int*   xlen = (const int*)d_in[1];
    const float* xlab = (const float*)d_in[2];
    const float* Wz   = (const float*)d_in[3];
    const float* Uz   = (const float*)d_in[4];
    const float* Wr   = (const float*)d_in[5];
    const float* Ur   = (const float*)d_in[6];
    const float* Wh   = (const float*)d_in[7];
    const float* Uh   = (const float*)d_in[8];
    const float* Wo   = (const float*)d_in[9];
    float* out = (float*)d_out;

    unsigned char* ws  = (unsigned char*)d_ws;
    unsigned char* wpU = ws;                                 // fp8 frags (9 mats), 576 KB
    unsigned char* wpW = ws + OFF_WPW;                       // bf16 W(l0) frags, 384 KB
    int*           FLG = (int*)(ws + OFF_FLG);               // flags + counters
    unsigned int*  XP  = (unsigned int*)(ws + OFF_XP);       // 25.2 MB
    unsigned int*  HP  = (unsigned int*)(ws + OFF_HP);       // 25.2 MB
    unsigned char* HN  = ws + OFF_HN;                        // fp8 hn0, 8.4 MB

    // ws re-poisoned every call -> rebuild everything (incl. flags) each time.
    prep_weights<<<1536, 256, 0, stream>>>(Wz, Wr, Wh, Uz, Ur, Uh, ws, out);
    fused_pipeline<<<2072, 1024, 0, stream>>>(x, XP, HP, wpU, wpW, HN,
                                              xlen, xlab, Wo, out, FLG);
}

// Round 13
// 1126.062 us; speedup vs baseline: 1.9356x; 1.0950x over previous
//
#include <hip/hip_runtime.h>

// Dims fixed by the reference
#define LAY 2
#define BATCH 64
#define TMAX 512
#define DIM 256
#define AST 264    // LDS activation row stride (bytes, fp8)
#define CHUNK 16   // pipeline handoff granularity (timesteps)

typedef float floatx4 __attribute__((ext_vector_type(4)));
typedef __bf16 bf16x8 __attribute__((ext_vector_type(8)));
#define MFMA_FP8  __builtin_amdgcn_mfma_f32_16x16x32_fp8_fp8
#define MFMA_BF16 __builtin_amdgcn_mfma_f32_16x16x32_bf16

// LDS-only barrier: orders ds ops (lgkmcnt) without draining vmcnt.
#define BAR_LDS() asm volatile("s_waitcnt lgkmcnt(0)\n\ts_barrier" ::: "memory")

// d_ws layout (requires ws >= ~74 MB)
#define OFF_WPW 0xA0000     // bf16 B-frag W(l0) mats, 3 x 128 KB (ends 0x100000)
#define OFF_FLG 0x150000    // [0..3] scan0 flags, [4..19] projB flags,
                            // [32..159] projA chunk counters (bg*32+chunk)
#define OFF_XP  0x200000    // layer-0 X-projections fp8 packed [t][nt][64][3], 25.2 MB
#define OFF_HP  0x1C00000   // layer-1 input projections fp8 packed, 25.2 MB
#define OFF_HN  0x3600000   // hn0 fp8 [b*512+t][256], 8.4 MB

__device__ __forceinline__ unsigned short f2bf(float f) {
    unsigned int u = __float_as_uint(f);
    unsigned int r = u + 0x7fffu + ((u >> 16) & 1u);  // RNE
    return (unsigned short)(r >> 16);
}
__device__ __forceinline__ unsigned int pk2(float a, float b) {
    return (unsigned int)__builtin_amdgcn_cvt_pk_fp8_f32(a, b, 0, false);  // OCP e4m3 x2
}
__device__ __forceinline__ unsigned char f2q(float a) { return (unsigned char)(pk2(a, a) & 0xff); }
__device__ __forceinline__ void unp4(unsigned int u, float* f) {
    auto lo = __builtin_amdgcn_cvt_pk_f32_fp8((int)u, false);
    auto hi = __builtin_amdgcn_cvt_pk_f32_fp8((int)u, true);
    f[0] = lo[0]; f[1] = lo[1]; f[2] = hi[0]; f[3] = hi[1];
}
// sigmoid via raw v_rcp_f32 (1 instr vs ~10-instr IEEE div sequence).
__device__ __forceinline__ float sigf(float x) {
    return __builtin_amdgcn_rcpf(1.f + __expf(-x));
}
// tanh(y) = 2*sigmoid(2y) - 1
__device__ __forceinline__ float tanhfast2y(float twoy) { return 2.f * sigf(twoy) - 1.f; }

// agent-scope relaxed store: device-coherent at the LLC (projA XP path only —
// R10 showed write-through costs extra HBM when applied to HN/HP, so those
// edges keep the R9 wbl2-release protocol)
__device__ __forceinline__ void ast_u32(unsigned int* p, unsigned int v) {
    __hip_atomic_store(p, v, __ATOMIC_RELAXED, __HIP_MEMORY_SCOPE_AGENT);
}

// In-register fp8 quantization of one 8-deep K-slice of a weight matrix:
// byte b of the returned long = fp8(8 * s[b*256]) — identical bit pattern to
// the old prep_weights fp8 section (verified mapping: uz[kf] byte b =
// fp8(8*U[kf*32+quad*8+b][nt*16+l15])).
__device__ __forceinline__ long quant8(const float* s) {
    unsigned int p01 = pk2(8.f * s[0 * 256], 8.f * s[1 * 256]);
    unsigned int p23 = pk2(8.f * s[2 * 256], 8.f * s[3 * 256]);
    unsigned int p45 = pk2(8.f * s[4 * 256], 8.f * s[5 * 256]);
    unsigned int p67 = pk2(8.f * s[6 * 256], 8.f * s[7 * 256]);
    unsigned long long v = (unsigned long long)(p01 & 0xffffu)
                         | ((unsigned long long)(p23 & 0xffffu) << 16)
                         | ((unsigned long long)(p45 & 0xffffu) << 32)
                         | ((unsigned long long)(p67 & 0xffffu) << 48);
    return (long)v;
}

// ---------------------------------------------------------------------------
// Weight prep: W(l0) bf16 B-frags ONLY (projA's input). U-frags and W(l1)
// frags are quantized in-register by their consuming blocks (overlaps their
// idle wait for projA chunk 0). Zeroes flags+counters (192 ints) and d_out.
// ---------------------------------------------------------------------------
__global__ void prep_weights(const float* __restrict__ Wz, const float* __restrict__ Wr,
                             const float* __restrict__ Wh,
                             unsigned char* __restrict__ ws, float* __restrict__ out) {
    int T = blockIdx.x * 256 + threadIdx.x;  // 384*256 = 98304
    if (T == 0) out[0] = 0.f;
    if (T < 192) ((int*)(ws + OFF_FLG))[T] = 0;  // flags + projA counters
    int e = T & 3, lane = (T >> 2) & 63;
    int kf = (T >> 8) & 7, nt = (T >> 11) & 15, mw = T >> 15;   // mw in 0..2
    const float* s = (mw == 0 ? Wz : mw == 1 ? Wr : Wh);        // layer 0
    int n  = nt * 16 + (lane & 15);
    int k0 = kf * 32 + (lane >> 4) * 8 + 2 * e;
    unsigned int v = (unsigned int)f2bf(s[(k0 << 8) + n]) |
                     ((unsigned int)f2bf(s[((k0 + 1) << 8) + n]) << 16);
    int addr = ((mw * 16 + nt) * 8 + kf) * 1024 + lane * 16 + 4 * e;
    *(unsigned int*)(ws + OFF_WPW + addr) = v;
}

// ---------------------------------------------------------------------------
// GRU scan body (R12 structure, 16 waves x 1 col-tile). WMODE: 1 = wait on
// MIN of 4 projB flags, 2 = wait on projA chunk counter == 16. POST: publish
// pflag per CHUNK (R9 protocol: plain HN stores, vmcnt drain at the
// __syncthreads, wbl2 release fence, flag). U fragments quantized in-register
// from the f32 source at prologue (bit-identical to old prep). XP/HP are
// packed [t][nt][64][3] -> one dwordx3 per lane per step.
// ---------------------------------------------------------------------------
template <int SCORE, int WMODE, int POST>
__device__ __forceinline__ void scan_body(
    const unsigned int* __restrict__ xp,
    const float* __restrict__ Uzs, const float* __restrict__ Urs,
    const float* __restrict__ Uhs,
    int bg, unsigned char* __restrict__ hnout,
    const int* __restrict__ xlen, const float* __restrict__ xlab,
    const float* __restrict__ Wo, float* __restrict__ out,
    int* wflags, int* pflag,
    unsigned char (*s1q)[AST], unsigned char (*rsq)[AST], float (*s1o)[264],
    float* wo1s, int* s_rdy, int tmax)
{
    const int tid = threadIdx.x, wave = tid >> 6, lane = tid & 63;
    const int l15 = lane & 15, quad = lane >> 4;
    const int b0 = bg * 16;

    for (int i = tid; i < 16 * AST; i += 1024) ((unsigned char*)s1q)[i] = 0;
    if (SCORE && tid < DIM) wo1s[tid] = Wo[2 * tid + 1];
    const int lenr = xlen[b0 + l15];
    const float labr = SCORE ? xlab[b0 + l15] : 0.f;
    (void)lenr; (void)labr;

    const int nt = wave;
    const int colA = nt * 16 + l15, rowb = quad * 4;

    // register-resident U fragments, quantized in-place from f32 source
    // (overlaps this block's wait for the upstream's first chunk)
    long uz[8], ur[8], uh[8];
    {
        const int nb = nt * 16 + l15;
#pragma unroll
        for (int kf = 0; kf < 8; ++kf) {
            const size_t kb = (size_t)(kf * 32 + quad * 8) * 256 + nb;
            uz[kf] = quant8(Uzs + kb);
            ur[kf] = quant8(Urs + kb);
            uh[kf] = quant8(Uhs + kb);
        }
    }
    float s1r[4] = {};
    float accl = 0.f;
    int ready = 0;
    __syncthreads();

    for (int t = 0; t < tmax; ++t) {
        if constexpr (WMODE == 1) {
            if (t >= ready) {
                if (tid == 0) {
                    int vv, g = 0;
                    for (;;) {
                        vv = 1 << 30;
#pragma unroll
                        for (int q = 0; q < 4; ++q) {
                            int m = __hip_atomic_load(wflags + q, __ATOMIC_RELAXED, __HIP_MEMORY_SCOPE_AGENT);
                            vv = m < vv ? m : vv;
                        }
                        if (vv > t || ++g > (1 << 19)) break;   // fail visibly, never hang
                        __builtin_amdgcn_s_sleep(2);
                    }
                    __threadfence();          // agent acquire before data reads
                    *s_rdy = vv > t ? vv : t + 1;
                }
                __syncthreads();
                ready = *s_rdy;
            }
        } else if constexpr (WMODE == 2) {
            if (t >= ready) {
                if (tid == 0) {
                    const int ch = t >> 4;    // CHUNK == 16
                    int g = 0;
                    for (;;) {
                        int c = __hip_atomic_load(wflags + ch, __ATOMIC_RELAXED, __HIP_MEMORY_SCOPE_AGENT);
                        if (c >= 16 || ++g > (1 << 19)) break;  // fail visibly, never hang
                        __builtin_amdgcn_s_sleep(2);
                    }
                    __threadfence();          // agent acquire: inv before XP reads
                    *s_rdy = (ch + 1) * CHUNK;
                }
                __syncthreads();
                ready = *s_rdy;
            }
        }

        // packed read: z,r,h adjacent per lane -> one dwordx3 (768B dense/wave)
        const unsigned int* xpt = xp + ((size_t)(bg * 512 + t) * 1024 + nt * 64 + lane) * 3;
        unsigned int xz = xpt[0];
        unsigned int xr = xpt[1];
        unsigned int xh = xpt[2];

        // ---- phase 1: r (on the critical path) + z-MFMAs (acc dangles) ----
        long sf[8];
#pragma unroll
        for (int kf = 0; kf < 8; ++kf) sf[kf] = *(const long*)&s1q[l15][kf * 32 + quad * 8];
        floatx4 za = {0.f, 0.f, 0.f, 0.f}, ra = za;
#pragma unroll
        for (int kf = 0; kf < 8; ++kf) {
            ra = MFMA_FP8(sf[kf], ur[kf], ra, 0, 0, 0);
            za = MFMA_FP8(sf[kf], uz[kf], za, 0, 0, 0);
        }
        float xrf[4];
        unp4(xr, xrf);
#pragma unroll
        for (int i = 0; i < 4; ++i) {
            float r = sigf(0.125f * ra[i] + 0.0625f * xrf[i]);
            rsq[rowb + i][colA] = f2q(r * s1r[i]);
        }
        BAR_LDS();   // LDS-only: XP loads / HN stores stay in flight

        // ---- phase 2: h; z-sigmoid overlaps the Uh MFMA ----
        long rf[8];
#pragma unroll
        for (int kf = 0; kf < 8; ++kf) rf[kf] = *(const long*)&rsq[l15][kf * 32 + quad * 8];
        floatx4 ha = {0.f, 0.f, 0.f, 0.f};
#pragma unroll
        for (int kf = 0; kf < 8; ++kf) ha = MFMA_FP8(rf[kf], uh[kf], ha, 0, 0, 0);
        float xzf[4], xhf[4];
        unp4(xz, xzf); unp4(xh, xhf);
#pragma unroll
        for (int i = 0; i < 4; ++i) {
            float z = sigf(0.125f * za[i] + 0.0625f * xzf[i]);
            float h = tanhfast2y(0.25f * ha[i] + 0.125f * xhf[i]);  // tanh(0.125ha+0.0625xh)
            float hn = fmaf(z, h - s1r[i], s1r[i]);   // (1-z)s1 + z h, folded
            s1r[i] = hn;
            s1q[rowb + i][colA] = f2q(hn);
            if (SCORE) s1o[rowb + i][colA] = hn;   // f32 copy only for scoring
        }
        BAR_LDS();   // LDS-only

        if (!SCORE) {
            // hn0 write, fp8: re-use s1q's bytes — 4B/thread, coalesced
            const int r = tid >> 6, c = (tid & 63) * 4;
            unsigned int v4 = *(const unsigned int*)&s1q[r][c];
            *(unsigned int*)(hnout + ((size_t)(b0 + r) * 512 + t) * 256 + c) = v4;
        } else if (wave == 0) {
            const int row = l15, c0 = quad * 64;
            float p = 0.f;
#pragma unroll
            for (int u = 0; u < 64; u += 4) {
                float4 sv = *(const float4*)&s1o[row][c0 + u];
                float4 wv = *(const float4*)&wo1s[c0 + u];
                p = fmaf(sv.x, wv.x, p); p = fmaf(sv.y, wv.y, p);
                p = fmaf(sv.z, wv.z, p); p = fmaf(sv.w, wv.w, p);
            }
            p += __shfl_xor(p, 16);
            p += __shfl_xor(p, 32);
            if (lane < 16 && t < lenr) {
                float sc = sigf(p);
                float d = labr - sc;
                accl = fmaf(d, d, accl);
            }
        }

        if (POST && (((t & (CHUNK - 1)) == (CHUNK - 1)) || t == tmax - 1)) {
            __syncthreads();   // FULL drain: all waves' HN stores (vmcnt0) before fence
            if (tid == 0) {
                __threadfence();   // agent release: push chunk data to coherent point
                __hip_atomic_store(pflag, t + 1, __ATOMIC_RELEASE, __HIP_MEMORY_SCOPE_AGENT);
            }
        }
    }

    if (SCORE && wave == 0) {
        accl += __shfl_xor(accl, 1);
        accl += __shfl_xor(accl, 2);
        accl += __shfl_xor(accl, 4);
        accl += __shfl_xor(accl, 8);
        if (lane == 0) atomicAdd(out, accl);
    }
}

// ---------------------------------------------------------------------------
// Fused pipeline + in-grid projA, 2072 WGs (R9 topology):
//   blocks 0-3   : layer-0 scan (waits projA counter==16 per chunk;
//                  posts flags[bg]; U(l0) frags quantized in prologue)
//   blocks 4-19  : projB, 4 WGs per bg; waits flags[bg], posts flags[4+bg*4+p]
//                  — fp8 A (HN) x fp8 B (W(l1), register-resident, quantized
//                  in prologue), out pk2(2*acc); packed HP dwordx3 stores
//   blocks 20-23 : layer-1 scan + loss (waits MIN of the bg's 4 projB flags;
//                  U(l1) frags quantized in prologue)
//   blocks 24-2071: projA, one (bg,t) each; agent-scope XP stores (packed
//                  [nt][64][3]) + chunk counter (cheap-producer protocol)
// ---------------------------------------------------------------------------
__global__ __launch_bounds__(1024, 4) void fused_pipeline(
    const float* __restrict__ x,
    unsigned int* __restrict__ XP, unsigned int* __restrict__ HP,
    const unsigned char* __restrict__ wpW, unsigned char* __restrict__ HN,
    const int* __restrict__ xlen, const float* __restrict__ xlab,
    const float* __restrict__ Wo, float* __restrict__ out, int* flags,
    const float* __restrict__ Uz, const float* __restrict__ Ur,
    const float* __restrict__ Uh,
    const float* __restrict__ Wz, const float* __restrict__ Wr,
    const float* __restrict__ Wh)
{
    __shared__ __align__(16) unsigned char s1q[16][AST];
    __shared__ __align__(16) unsigned char rsq[16][AST];
    __shared__ __align__(16) float s1o[16][264];
    __shared__ float wo1s[DIM];
    __shared__ int s_rdy;

    const int bid = blockIdx.x;
    const int tid = threadIdx.x, wave = tid >> 6, lane = tid & 63;
    const int l15 = lane & 15, quad = lane >> 4;
    int* cnt = flags + 32;   // projA chunk counters, bg*32+chunk

    if (bid >= 24) {
        // ---- projA: XP[t] = x[t] @ W(l0); one (bg,t) per block ----
        const int idx = bid - 24;            // 0..2047
        const int pt = idx & 511, pbg = idx >> 9;
        const float* s = x + ((size_t)(pbg * 16 + l15) * 512 + pt) * 256;
        bf16x8 af[8];
#pragma unroll
        for (int kf = 0; kf < 8; ++kf) {
            float4 a = *(const float4*)(s + kf * 32 + quad * 8);
            float4 b = *(const float4*)(s + kf * 32 + quad * 8 + 4);
            union { unsigned short u[8]; bf16x8 v; } cv;
            cv.u[0] = f2bf(a.x); cv.u[1] = f2bf(a.y); cv.u[2] = f2bf(a.z); cv.u[3] = f2bf(a.w);
            cv.u[4] = f2bf(b.x); cv.u[5] = f2bf(b.y); cv.u[6] = f2bf(b.z); cv.u[7] = f2bf(b.w);
            af[kf] = cv.v;
        }
        floatx4 az = {0.f, 0.f, 0.f, 0.f}, ar = az, ah = az;
        const unsigned char* bz = wpW + (size_t)((0 * 16 + wave) * 8) * 1024 + lane * 16;
        const unsigned char* br = wpW + (size_t)((1 * 16 + wave) * 8) * 1024 + lane * 16;
        const unsigned char* bh = wpW + (size_t)((2 * 16 + wave) * 8) * 1024 + lane * 16;
#pragma unroll
        for (int kf = 0; kf < 8; ++kf) {
            az = MFMA_BF16(af[kf], *(const bf16x8*)(bz + kf * 1024), az, 0, 0, 0);
            ar = MFMA_BF16(af[kf], *(const bf16x8*)(br + kf * 1024), ar, 0, 0, 0);
            ah = MFMA_BF16(af[kf], *(const bf16x8*)(bh + kf * 1024), ah, 0, 0, 0);
        }
        // packed store: z,r,h adjacent per lane (consecutive dwords)
        const size_t ob3 = ((size_t)(pbg * 512 + pt) * 1024 + wave * 64 + lane) * 3;
        ast_u32(&XP[ob3 + 0], pk2(16.f * az[0], 16.f * az[1]) | (pk2(16.f * az[2], 16.f * az[3]) << 16));
        ast_u32(&XP[ob3 + 1], pk2(16.f * ar[0], 16.f * ar[1]) | (pk2(16.f * ar[2], 16.f * ar[3]) << 16));
        ast_u32(&XP[ob3 + 2], pk2(16.f * ah[0], 16.f * ah[1]) | (pk2(16.f * ah[2], 16.f * ah[3]) << 16));
        __syncthreads();   // vmcnt(0): all block's coherent stores complete
        if (tid == 0)
            __hip_atomic_fetch_add(cnt + pbg * 32 + (pt >> 4), 1,
                                   __ATOMIC_RELAXED, __HIP_MEMORY_SCOPE_AGENT);
        return;
    }

    int role, bg, p = 0;
    if (bid < 4)       { role = 0; bg = bid; }
    else if (bid < 20) { role = 1; bg = (bid - 4) >> 2; p = (bid - 4) & 3; }
    else               { role = 2; bg = bid - 20; }
    const int b0 = bg * 16;

    // uniform tmax = max xlen over this bg's 16 rows (same in all stages)
    int v = xlen[b0 + l15];
#pragma unroll
    for (int o = 1; o < 16; o <<= 1) v = max(v, __shfl_xor(v, o));
    const int tmax = __builtin_amdgcn_readfirstlane(v);

    if (role == 0) {
        scan_body<0, 2, 1>(XP, Uz, Ur, Uh, bg, HN, xlen, xlab, Wo, out,
                           cnt + bg * 32, flags + bg, s1q, rsq, s1o, wo1s, &s_rdy, tmax);
    } else if (role == 2) {
        scan_body<1, 1, 0>(HP, Uz + 65536, Ur + 65536, Uh + 65536, bg, nullptr,
                           xlen, xlab, Wo, out,
                           flags + 4 + bg * 4, nullptr, s1q, rsq, s1o, wo1s, &s_rdy, tmax);
    } else {
        // ---- projB: HP[t] = HN[t] @ W(l1), fp8 x fp8; 4 t per chunk ----
        int* wf = flags + bg;
        int* pf = flags + 4 + bg * 4 + p;
        const int nt = wave;
        // register-resident W(l1) fp8 B-frags, quantized in prologue
        long wz1[8], wr1[8], wh1[8];
        {
            const int nb = nt * 16 + l15;
#pragma unroll
            for (int kf = 0; kf < 8; ++kf) {
                const size_t kb = (size_t)(kf * 32 + quad * 8) * 256 + nb;
                wz1[kf] = quant8(Wz + 65536 + kb);
                wr1[kf] = quant8(Wr + 65536 + kb);
                wh1[kf] = quant8(Wh + 65536 + kb);
            }
        }
        for (int base = 0; base < tmax; base += CHUNK) {
            const int target = (base + CHUNK < tmax) ? base + CHUNK : tmax;
            if (tid == 0) {
                int vv, g = 0;
                for (;;) {
                    vv = __hip_atomic_load(wf, __ATOMIC_RELAXED, __HIP_MEMORY_SCOPE_AGENT);
                    if (vv >= target || ++g > (1 << 19)) break;
                    __builtin_amdgcn_s_sleep(2);
                }
                __threadfence();   // acquire: inv before reading scan0's HN chunk
            }
            __syncthreads();       // no wave reads HN before the inv

            const int t0 = base + p * 4;
            const int t1 = (t0 + 4 < tmax) ? t0 + 4 : tmax;
            for (int t = t0; t < t1; ++t) {
                const unsigned char* sA = HN + ((size_t)(b0 + l15) * 512 + t) * 256;
                long af[8];
#pragma unroll
                for (int kf = 0; kf < 8; ++kf) af[kf] = *(const long*)(sA + kf * 32 + quad * 8);
                floatx4 az = {0.f, 0.f, 0.f, 0.f}, ar = az, ah = az;
#pragma unroll
                for (int kf = 0; kf < 8; ++kf) {
                    az = MFMA_FP8(af[kf], wz1[kf], az, 0, 0, 0);
                    ar = MFMA_FP8(af[kf], wr1[kf], ar, 0, 0, 0);
                    ah = MFMA_FP8(af[kf], wh1[kf], ah, 0, 0, 0);
                }
                // acc = hn * (8W) -> want pk2(16 * hn*W) = pk2(2 * acc)
                // packed store: one dwordx3 per lane (dense 768B/wave)
                const size_t ob3 = ((size_t)(bg * 512 + t) * 1024 + nt * 64 + lane) * 3;
                HP[ob3 + 0] = pk2(2.f * az[0], 2.f * az[1]) | (pk2(2.f * az[2], 2.f * az[3]) << 16);
                HP[ob3 + 1] = pk2(2.f * ar[0], 2.f * ar[1]) | (pk2(2.f * ar[2], 2.f * ar[3]) << 16);
                HP[ob3 + 2] = pk2(2.f * ah[0], 2.f * ah[1]) | (pk2(2.f * ah[2], 2.f * ah[3]) << 16);
            }

            __syncthreads();   // all waves' HP stores drained (vmcnt0 before barrier)
            if (tid == 0) {
                __threadfence();   // release: push HP chunk to coherent point
                __hip_atomic_store(pf, base + CHUNK, __ATOMIC_RELEASE, __HIP_MEMORY_SCOPE_AGENT);
            }
        }
    }
}

extern "C" void kernel_launch(void* const* d_in, const int* in_sizes, int n_in,
                              void* d_out, int out_size, void* d_ws, size_t ws_size,
                              hipStream_t stream) {
    const float* x    = (const float*)d_in[0];
    const int*   xlen = (const int*)d_in[1];
    const float* xlab = (const float*)d_in[2];
    const float* Wz   = (const float*)d_in[3];
    const float* Uz   = (const float*)d_in[4];
    const float* Wr   = (const float*)d_in[5];
    const float* Ur   = (const float*)d_in[6];
    const float* Wh   = (const float*)d_in[7];
    const float* Uh   = (const float*)d_in[8];
    const float* Wo   = (const float*)d_in[9];
    float* out = (float*)d_out;

    unsigned char* ws  = (unsigned char*)d_ws;
    unsigned char* wpW = ws + OFF_WPW;                       // bf16 W(l0) frags, 384 KB
    int*           FLG = (int*)(ws + OFF_FLG);               // flags + counters
    unsigned int*  XP  = (unsigned int*)(ws + OFF_XP);       // 25.2 MB packed
    unsigned int*  HP  = (unsigned int*)(ws + OFF_HP);       // 25.2 MB packed
    unsigned char* HN  = ws + OFF_HN;                        // fp8 hn0, 8.4 MB

    // ws re-poisoned every call -> rebuild everything (incl. flags) each time.
    prep_weights<<<384, 256, 0, stream>>>(Wz, Wr, Wh, ws, out);
    fused_pipeline<<<2072, 1024, 0, stream>>>(x, XP, HP, wpW, HN,
                                              xlen, xlab, Wo, out, FLG,
                                              Uz, Ur, Uh, Wz, Wr, Wh);
}

// Round 14
// 1081.094 us; speedup vs baseline: 2.0162x; 1.0416x over previous
//
#include <hip/hip_runtime.h>

// Dims fixed by the reference
#define LAY 2
#define BATCH 64
#define TMAX 512
#define DIM 256
#define AST 264    // LDS activation row stride (bytes, fp8)
#define CHUNK 16   // pipeline handoff granularity (timesteps)

typedef float floatx4 __attribute__((ext_vector_type(4)));
typedef __bf16 bf16x8 __attribute__((ext_vector_type(8)));
#define MFMA_FP8  __builtin_amdgcn_mfma_f32_16x16x32_fp8_fp8
#define MFMA_BF16 __builtin_amdgcn_mfma_f32_16x16x32_bf16

// LDS-only barrier: orders ds ops (lgkmcnt) without draining vmcnt.
#define BAR_LDS() asm volatile("s_waitcnt lgkmcnt(0)\n\ts_barrier" ::: "memory")

// d_ws layout (requires ws >= ~74 MB)
#define OFF_WPW 0xA0000     // bf16 B-frag W(l0) mats, 3 x 128 KB (ends 0x100000)
#define OFF_FLG 0x150000    // [0..3] scan0 flags, [4..19] projB flags,
                            // [32..159] projA chunk counters (bg*32+chunk)
#define OFF_XP  0x200000    // layer-0 X-projections fp8 packed [t][nt][64][3], 25.2 MB
#define OFF_HP  0x1C00000   // layer-1 input projections fp8 packed, 25.2 MB
#define OFF_HN  0x3600000   // hn0 fp8 [b*512+t][256], 8.4 MB

__device__ __forceinline__ unsigned short f2bf(float f) {
    unsigned int u = __float_as_uint(f);
    unsigned int r = u + 0x7fffu + ((u >> 16) & 1u);  // RNE
    return (unsigned short)(r >> 16);
}
__device__ __forceinline__ unsigned int pk2(float a, float b) {
    return (unsigned int)__builtin_amdgcn_cvt_pk_fp8_f32(a, b, 0, false);  // OCP e4m3 x2
}
__device__ __forceinline__ unsigned char f2q(float a) { return (unsigned char)(pk2(a, a) & 0xff); }
__device__ __forceinline__ void unp4(unsigned int u, float* f) {
    auto lo = __builtin_amdgcn_cvt_pk_f32_fp8((int)u, false);
    auto hi = __builtin_amdgcn_cvt_pk_f32_fp8((int)u, true);
    f[0] = lo[0]; f[1] = lo[1]; f[2] = hi[0]; f[3] = hi[1];
}
// sigmoid via raw v_rcp_f32 (1 instr vs ~10-instr IEEE div sequence).
__device__ __forceinline__ float sigf(float x) {
    return __builtin_amdgcn_rcpf(1.f + __expf(-x));
}
// tanh(y) = 2*sigmoid(2y) - 1
__device__ __forceinline__ float tanhfast2y(float twoy) { return 2.f * sigf(twoy) - 1.f; }

// agent-scope relaxed store: device-coherent at the LLC (projA XP path only —
// R10 showed write-through costs extra HBM when applied to HN/HP, so those
// edges keep the R9 wbl2-release protocol)
__device__ __forceinline__ void ast_u32(unsigned int* p, unsigned int v) {
    __hip_atomic_store(p, v, __ATOMIC_RELAXED, __HIP_MEMORY_SCOPE_AGENT);
}

// In-register fp8 quantization of one 8-deep K-slice of a weight matrix:
// byte b of the returned long = fp8(8 * s[b*256]) — bit-identical to the old
// prep_weights fp8 section.
__device__ __forceinline__ long quant8(const float* s) {
    unsigned int p01 = pk2(8.f * s[0 * 256], 8.f * s[1 * 256]);
    unsigned int p23 = pk2(8.f * s[2 * 256], 8.f * s[3 * 256]);
    unsigned int p45 = pk2(8.f * s[4 * 256], 8.f * s[5 * 256]);
    unsigned int p67 = pk2(8.f * s[6 * 256], 8.f * s[7 * 256]);
    unsigned long long v = (unsigned long long)(p01 & 0xffffu)
                         | ((unsigned long long)(p23 & 0xffffu) << 16)
                         | ((unsigned long long)(p45 & 0xffffu) << 32)
                         | ((unsigned long long)(p67 & 0xffffu) << 48);
    return (long)v;
}

// ---------------------------------------------------------------------------
// Weight prep: W(l0) bf16 B-frags ONLY (projA's input). U-frags and W(l1)
// frags are quantized in-register by their consuming blocks. Zeroes
// flags+counters (192 ints) and d_out.
// ---------------------------------------------------------------------------
__global__ void prep_weights(const float* __restrict__ Wz, const float* __restrict__ Wr,
                             const float* __restrict__ Wh,
                             unsigned char* __restrict__ ws, float* __restrict__ out) {
    int T = blockIdx.x * 256 + threadIdx.x;  // 384*256 = 98304
    if (T == 0) out[0] = 0.f;
    if (T < 192) ((int*)(ws + OFF_FLG))[T] = 0;  // flags + projA counters
    int e = T & 3, lane = (T >> 2) & 63;
    int kf = (T >> 8) & 7, nt = (T >> 11) & 15, mw = T >> 15;   // mw in 0..2
    const float* s = (mw == 0 ? Wz : mw == 1 ? Wr : Wh);        // layer 0
    int n  = nt * 16 + (lane & 15);
    int k0 = kf * 32 + (lane >> 4) * 8 + 2 * e;
    unsigned int v = (unsigned int)f2bf(s[(k0 << 8) + n]) |
                     ((unsigned int)f2bf(s[((k0 + 1) << 8) + n]) << 16);
    int addr = ((mw * 16 + nt) * 8 + kf) * 1024 + lane * 16 + 4 * e;
    *(unsigned int*)(ws + OFF_WPW + addr) = v;
}

// ---------------------------------------------------------------------------
// GRU scan body (16 waves x 1 col-tile). WMODE: 1 = wait on MIN of 4 projB
// flags, 2 = wait on projA chunk counter == 16 (ready extended across ALL
// completed chunks -> one acquire-inv covers many chunks once projA is done).
// POST: publish pflag per CHUNK (R9 protocol). U fragments quantized
// in-register at prologue. XP/HP packed [t][nt][64][3] -> one dwordx3/lane.
// MFMA accumulate chains split 2x (4+4) to halve dep-latency on the serial
// recurrence path.
// ---------------------------------------------------------------------------
template <int SCORE, int WMODE, int POST>
__device__ __forceinline__ void scan_body(
    const unsigned int* __restrict__ xp,
    const float* __restrict__ Uzs, const float* __restrict__ Urs,
    const float* __restrict__ Uhs,
    int bg, unsigned char* __restrict__ hnout,
    const int* __restrict__ xlen, const float* __restrict__ xlab,
    const float* __restrict__ Wo, float* __restrict__ out,
    int* wflags, int* pflag,
    unsigned char (*s1q)[AST], unsigned char (*rsq)[AST], float (*s1o)[264],
    float* wo1s, int* s_rdy, int tmax)
{
    const int tid = threadIdx.x, wave = tid >> 6, lane = tid & 63;
    const int l15 = lane & 15, quad = lane >> 4;
    const int b0 = bg * 16;

    for (int i = tid; i < 16 * AST; i += 1024) ((unsigned char*)s1q)[i] = 0;
    if (SCORE && tid < DIM) wo1s[tid] = Wo[2 * tid + 1];
    const int lenr = xlen[b0 + l15];
    const float labr = SCORE ? xlab[b0 + l15] : 0.f;
    (void)lenr; (void)labr;

    const int nt = wave;
    const int colA = nt * 16 + l15, rowb = quad * 4;

    // register-resident U fragments, quantized in-place from f32 source
    long uz[8], ur[8], uh[8];
    {
        const int nb = nt * 16 + l15;
#pragma unroll
        for (int kf = 0; kf < 8; ++kf) {
            const size_t kb = (size_t)(kf * 32 + quad * 8) * 256 + nb;
            uz[kf] = quant8(Uzs + kb);
            ur[kf] = quant8(Urs + kb);
            uh[kf] = quant8(Uhs + kb);
        }
    }
    float s1r[4] = {};
    float accl = 0.f;
    int ready = 0;
    __syncthreads();

    for (int t = 0; t < tmax; ++t) {
        if constexpr (WMODE == 1) {
            if (t >= ready) {
                if (tid == 0) {
                    int vv, g = 0;
                    for (;;) {
                        vv = 1 << 30;
#pragma unroll
                        for (int q = 0; q < 4; ++q) {
                            int m = __hip_atomic_load(wflags + q, __ATOMIC_RELAXED, __HIP_MEMORY_SCOPE_AGENT);
                            vv = m < vv ? m : vv;
                        }
                        if (vv > t || ++g > (1 << 19)) break;   // fail visibly, never hang
                        __builtin_amdgcn_s_sleep(2);
                    }
                    __threadfence();          // agent acquire before data reads
                    *s_rdy = vv > t ? vv : t + 1;
                }
                __syncthreads();
                ready = *s_rdy;
            }
        } else if constexpr (WMODE == 2) {
            if (t >= ready) {
                if (tid == 0) {
                    const int ch = t >> 4;    // CHUNK == 16
                    int g = 0;
                    for (;;) {
                        int c = __hip_atomic_load(wflags + ch, __ATOMIC_RELAXED, __HIP_MEMORY_SCOPE_AGENT);
                        if (c >= 16 || ++g > (1 << 19)) break;  // fail visibly, never hang
                        __builtin_amdgcn_s_sleep(2);
                    }
                    // extend across all already-complete chunks: ONE inv
                    // covers them all (projA finishes in the first ~30us)
                    int ch2 = ch + 1;
                    while (ch2 < TMAX / CHUNK &&
                           __hip_atomic_load(wflags + ch2, __ATOMIC_RELAXED,
                                             __HIP_MEMORY_SCOPE_AGENT) >= 16) ++ch2;
                    __threadfence();          // agent acquire: inv before XP reads
                    *s_rdy = ch2 * CHUNK;
                }
                __syncthreads();
                ready = *s_rdy;
            }
        }

        // packed read: z,r,h adjacent per lane -> one dwordx3 (768B dense/wave)
        const unsigned int* xpt = xp + ((size_t)(bg * 512 + t) * 1024 + nt * 64 + lane) * 3;
        unsigned int xz = xpt[0];
        unsigned int xr = xpt[1];
        unsigned int xh = xpt[2];

        // ---- phase 1: r (critical path) + z-MFMAs; chains split 4+4 ----
        long sf[8];
#pragma unroll
        for (int kf = 0; kf < 8; ++kf) sf[kf] = *(const long*)&s1q[l15][kf * 32 + quad * 8];
        floatx4 zer = {0.f, 0.f, 0.f, 0.f};
        floatx4 ra0 = zer, ra1 = zer, za0 = zer, za1 = zer;
#pragma unroll
        for (int kf = 0; kf < 4; ++kf) {
            ra0 = MFMA_FP8(sf[kf],     ur[kf],     ra0, 0, 0, 0);
            ra1 = MFMA_FP8(sf[kf + 4], ur[kf + 4], ra1, 0, 0, 0);
            za0 = MFMA_FP8(sf[kf],     uz[kf],     za0, 0, 0, 0);
            za1 = MFMA_FP8(sf[kf + 4], uz[kf + 4], za1, 0, 0, 0);
        }
        floatx4 ra = ra0 + ra1;
        float xrf[4];
        unp4(xr, xrf);
#pragma unroll
        for (int i = 0; i < 4; ++i) {
            float r = sigf(0.125f * ra[i] + 0.0625f * xrf[i]);
            rsq[rowb + i][colA] = f2q(r * s1r[i]);
        }
        BAR_LDS();   // LDS-only: XP loads / HN stores stay in flight

        // ---- phase 2: h (split 4+4); z-sigmoid overlaps the Uh MFMA ----
        long rf[8];
#pragma unroll
        for (int kf = 0; kf < 8; ++kf) rf[kf] = *(const long*)&rsq[l15][kf * 32 + quad * 8];
        floatx4 ha0 = zer, ha1 = zer;
#pragma unroll
        for (int kf = 0; kf < 4; ++kf) {
            ha0 = MFMA_FP8(rf[kf],     uh[kf],     ha0, 0, 0, 0);
            ha1 = MFMA_FP8(rf[kf + 4], uh[kf + 4], ha1, 0, 0, 0);
        }
        floatx4 ha = ha0 + ha1;
        floatx4 za = za0 + za1;
        float xzf[4], xhf[4];
        unp4(xz, xzf); unp4(xh, xhf);
#pragma unroll
        for (int i = 0; i < 4; ++i) {
            float z = sigf(0.125f * za[i] + 0.0625f * xzf[i]);
            float h = tanhfast2y(0.25f * ha[i] + 0.125f * xhf[i]);  // tanh(0.125ha+0.0625xh)
            float hn = fmaf(z, h - s1r[i], s1r[i]);   // (1-z)s1 + z h, folded
            s1r[i] = hn;
            s1q[rowb + i][colA] = f2q(hn);
            if (SCORE) s1o[rowb + i][colA] = hn;   // f32 copy only for scoring
        }
        BAR_LDS();   // LDS-only

        if (!SCORE) {
            // hn0 write, fp8: re-use s1q's bytes — 4B/thread, coalesced
            const int r = tid >> 6, c = (tid & 63) * 4;
            unsigned int v4 = *(const unsigned int*)&s1q[r][c];
            *(unsigned int*)(hnout + ((size_t)(b0 + r) * 512 + t) * 256 + c) = v4;
        } else if (wave == 0) {
            const int row = l15, c0 = quad * 64;
            float p = 0.f;
#pragma unroll
            for (int u = 0; u < 64; u += 4) {
                float4 sv = *(const float4*)&s1o[row][c0 + u];
                float4 wv = *(const float4*)&wo1s[c0 + u];
                p = fmaf(sv.x, wv.x, p); p = fmaf(sv.y, wv.y, p);
                p = fmaf(sv.z, wv.z, p); p = fmaf(sv.w, wv.w, p);
            }
            p += __shfl_xor(p, 16);
            p += __shfl_xor(p, 32);
            if (lane < 16 && t < lenr) {
                float sc = sigf(p);
                float d = labr - sc;
                accl = fmaf(d, d, accl);
            }
        }

        if (POST && (((t & (CHUNK - 1)) == (CHUNK - 1)) || t == tmax - 1)) {
            __syncthreads();   // FULL drain: all waves' HN stores (vmcnt0) before fence
            if (tid == 0) {
                __threadfence();   // agent release: push chunk data to coherent point
                __hip_atomic_store(pflag, t + 1, __ATOMIC_RELEASE, __HIP_MEMORY_SCOPE_AGENT);
            }
        }
    }

    if (SCORE && wave == 0) {
        accl += __shfl_xor(accl, 1);
        accl += __shfl_xor(accl, 2);
        accl += __shfl_xor(accl, 4);
        accl += __shfl_xor(accl, 8);
        if (lane == 0) atomicAdd(out, accl);
    }
}

// ---------------------------------------------------------------------------
// Fused pipeline + in-grid projA, 2072 WGs (R9 topology):
//   blocks 0-3   : layer-0 scan (waits projA counter==16 per chunk;
//                  posts flags[bg]; U(l0) frags quantized in prologue)
//   blocks 4-19  : projB, 4 WGs per bg; waits flags[bg], posts flags[4+bg*4+p]
//                  — fp8 A (HN) x fp8 B (W(l1), register-resident), out
//                  pk2(2*acc); packed HP dwordx3 stores (write-back + wbl2)
//   blocks 20-23 : layer-1 scan + loss (waits MIN of the bg's 4 projB flags;
//                  U(l1) frags quantized in prologue)
//   blocks 24-2071: projA, one (bg,t) each; packed XP staged through LDS so
//                  the agent-scope (write-through) stores are instruction-
//                  dense — avoids the 3x write amplification R13 measured.
// ---------------------------------------------------------------------------
__global__ __launch_bounds__(1024, 4) void fused_pipeline(
    const float* __restrict__ x,
    unsigned int* __restrict__ XP, unsigned int* __restrict__ HP,
    const unsigned char* __restrict__ wpW, unsigned char* __restrict__ HN,
    const int* __restrict__ xlen, const float* __restrict__ xlab,
    const float* __restrict__ Wo, float* __restrict__ out, int* flags,
    const float* __restrict__ Uz, const float* __restrict__ Ur,
    const float* __restrict__ Uh,
    const float* __restrict__ Wz, const float* __restrict__ Wr,
    const float* __restrict__ Wh)
{
    __shared__ __align__(16) unsigned char s1q[16][AST];
    __shared__ __align__(16) unsigned char rsq[16][AST];
    __shared__ __align__(16) float s1o[16][264];
    __shared__ float wo1s[DIM];
    __shared__ int s_rdy;
    __shared__ __align__(16) unsigned int xpstage[3072];   // projA store stage

    const int bid = blockIdx.x;
    const int tid = threadIdx.x, wave = tid >> 6, lane = tid & 63;
    const int l15 = lane & 15, quad = lane >> 4;
    int* cnt = flags + 32;   // projA chunk counters, bg*32+chunk

    if (bid >= 24) {
        // ---- projA: XP[t] = x[t] @ W(l0); one (bg,t) per block ----
        const int idx = bid - 24;            // 0..2047
        const int pt = idx & 511, pbg = idx >> 9;
        const float* s = x + ((size_t)(pbg * 16 + l15) * 512 + pt) * 256;
        bf16x8 af[8];
#pragma unroll
        for (int kf = 0; kf < 8; ++kf) {
            float4 a = *(const float4*)(s + kf * 32 + quad * 8);
            float4 b = *(const float4*)(s + kf * 32 + quad * 8 + 4);
            union { unsigned short u[8]; bf16x8 v; } cv;
            cv.u[0] = f2bf(a.x); cv.u[1] = f2bf(a.y); cv.u[2] = f2bf(a.z); cv.u[3] = f2bf(a.w);
            cv.u[4] = f2bf(b.x); cv.u[5] = f2bf(b.y); cv.u[6] = f2bf(b.z); cv.u[7] = f2bf(b.w);
            af[kf] = cv.v;
        }
        floatx4 az = {0.f, 0.f, 0.f, 0.f}, ar = az, ah = az;
        const unsigned char* bz = wpW + (size_t)((0 * 16 + wave) * 8) * 1024 + lane * 16;
        const unsigned char* br = wpW + (size_t)((1 * 16 + wave) * 8) * 1024 + lane * 16;
        const unsigned char* bh = wpW + (size_t)((2 * 16 + wave) * 8) * 1024 + lane * 16;
#pragma unroll
        for (int kf = 0; kf < 8; ++kf) {
            az = MFMA_BF16(af[kf], *(const bf16x8*)(bz + kf * 1024), az, 0, 0, 0);
            ar = MFMA_BF16(af[kf], *(const bf16x8*)(br + kf * 1024), ar, 0, 0, 0);
            ah = MFMA_BF16(af[kf], *(const bf16x8*)(bh + kf * 1024), ah, 0, 0, 0);
        }
        // stage packed dwords in LDS (stride-3 writes: 2 lanes/bank = free),
        // then instruction-dense agent-scope stores (256B/wave contiguous)
        xpstage[tid * 3 + 0] = pk2(16.f * az[0], 16.f * az[1]) | (pk2(16.f * az[2], 16.f * az[3]) << 16);
        xpstage[tid * 3 + 1] = pk2(16.f * ar[0], 16.f * ar[1]) | (pk2(16.f * ar[2], 16.f * ar[3]) << 16);
        xpstage[tid * 3 + 2] = pk2(16.f * ah[0], 16.f * ah[1]) | (pk2(16.f * ah[2], 16.f * ah[3]) << 16);
        __syncthreads();
        const size_t base3 = (size_t)(pbg * 512 + pt) * 3072;
        ast_u32(&XP[base3 + tid],        xpstage[tid]);
        ast_u32(&XP[base3 + 1024 + tid], xpstage[1024 + tid]);
        ast_u32(&XP[base3 + 2048 + tid], xpstage[2048 + tid]);
        __syncthreads();   // vmcnt(0): all block's coherent stores complete
        if (tid == 0)
            __hip_atomic_fetch_add(cnt + pbg * 32 + (pt >> 4), 1,
                                   __ATOMIC_RELAXED, __HIP_MEMORY_SCOPE_AGENT);
        return;
    }

    int role, bg, p = 0;
    if (bid < 4)       { role = 0; bg = bid; }
    else if (bid < 20) { role = 1; bg = (bid - 4) >> 2; p = (bid - 4) & 3; }
    else               { role = 2; bg = bid - 20; }
    const int b0 = bg * 16;

    // uniform tmax = max xlen over this bg's 16 rows (same in all stages)
    int v = xlen[b0 + l15];
#pragma unroll
    for (int o = 1; o < 16; o <<= 1) v = max(v, __shfl_xor(v, o));
    const int tmax = __builtin_amdgcn_readfirstlane(v);

    if (role == 0) {
        scan_body<0, 2, 1>(XP, Uz, Ur, Uh, bg, HN, xlen, xlab, Wo, out,
                           cnt + bg * 32, flags + bg, s1q, rsq, s1o, wo1s, &s_rdy, tmax);
    } else if (role == 2) {
        scan_body<1, 1, 0>(HP, Uz + 65536, Ur + 65536, Uh + 65536, bg, nullptr,
                           xlen, xlab, Wo, out,
                           flags + 4 + bg * 4, nullptr, s1q, rsq, s1o, wo1s, &s_rdy, tmax);
    } else {
        // ---- projB: HP[t] = HN[t] @ W(l1), fp8 x fp8; 4 t per chunk ----
        int* wf = flags + bg;
        int* pf = flags + 4 + bg * 4 + p;
        const int nt = wave;
        // register-resident W(l1) fp8 B-frags, quantized in prologue
        long wz1[8], wr1[8], wh1[8];
        {
            const int nb = nt * 16 + l15;
#pragma unroll
            for (int kf = 0; kf < 8; ++kf) {
                const size_t kb = (size_t)(kf * 32 + quad * 8) * 256 + nb;
                wz1[kf] = quant8(Wz + 65536 + kb);
                wr1[kf] = quant8(Wr + 65536 + kb);
                wh1[kf] = quant8(Wh + 65536 + kb);
            }
        }
        for (int base = 0; base < tmax; base += CHUNK) {
            const int target = (base + CHUNK < tmax) ? base + CHUNK : tmax;
            if (tid == 0) {
                int vv, g = 0;
                for (;;) {
                    vv = __hip_atomic_load(wf, __ATOMIC_RELAXED, __HIP_MEMORY_SCOPE_AGENT);
                    if (vv >= target || ++g > (1 << 19)) break;
                    __builtin_amdgcn_s_sleep(2);
                }
                __threadfence();   // acquire: inv before reading scan0's HN chunk
            }
            __syncthreads();       // no wave reads HN before the inv

            const int t0 = base + p * 4;
            const int t1 = (t0 + 4 < tmax) ? t0 + 4 : tmax;
            for (int t = t0; t < t1; ++t) {
                const unsigned char* sA = HN + ((size_t)(b0 + l15) * 512 + t) * 256;
                long af[8];
#pragma unroll
                for (int kf = 0; kf < 8; ++kf) af[kf] = *(const long*)(sA + kf * 32 + quad * 8);
                floatx4 az = {0.f, 0.f, 0.f, 0.f}, ar = az, ah = az;
#pragma unroll
                for (int kf = 0; kf < 8; ++kf) {
                    az = MFMA_FP8(af[kf], wz1[kf], az, 0, 0, 0);
                    ar = MFMA_FP8(af[kf], wr1[kf], ar, 0, 0, 0);
                    ah = MFMA_FP8(af[kf], wh1[kf], ah, 0, 0, 0);
                }
                // acc = hn * (8W) -> want pk2(16 * hn*W) = pk2(2 * acc)
                // packed store: write-back cached (merges in L2), wbl2 at POST
                const size_t ob3 = ((size_t)(bg * 512 + t) * 1024 + nt * 64 + lane) * 3;
                HP[ob3 + 0] = pk2(2.f * az[0], 2.f * az[1]) | (pk2(2.f * az[2], 2.f * az[3]) << 16);
                HP[ob3 + 1] = pk2(2.f * ar[0], 2.f * ar[1]) | (pk2(2.f * ar[2], 2.f * ar[3]) << 16);
                HP[ob3 + 2] = pk2(2.f * ah[0], 2.f * ah[1]) | (pk2(2.f * ah[2], 2.f * ah[3]) << 16);
            }

            __syncthreads();   // all waves' HP stores drained (vmcnt0 before barrier)
            if (tid == 0) {
                __threadfence();   // release: push HP chunk to coherent point
                __hip_atomic_store(pf, base + CHUNK, __ATOMIC_RELEASE, __HIP_MEMORY_SCOPE_AGENT);
            }
        }
    }
}

extern "C" void kernel_launch(void* const* d_in, const int* in_sizes, int n_in,
                              void* d_out, int out_size, void* d_ws, size_t ws_size,
                              hipStream_t stream) {
    const float* x    = (const float*)d_in[0];
    const int*   xlen = (const int*)d_in[1];
    const float* xlab = (const float*)d_in[2];
    const float* Wz   = (const float*)d_in[3];
    const float* Uz   = (const float*)d_in[4];
    const float* Wr   = (const float*)d_in[5];
    const float* Ur   = (const float*)d_in[6];
    const float* Wh   = (const float*)d_in[7];
    const float* Uh   = (const float*)d_in[8];
    const float* Wo   = (const float*)d_in[9];
    float* out = (float*)d_out;

    unsigned char* ws  = (unsigned char*)d_ws;
    unsigned char* wpW = ws + OFF_WPW;                       // bf16 W(l0) frags, 384 KB
    int*           FLG = (int*)(ws + OFF_FLG);               // flags + counters
    unsigned int*  XP  = (unsigned int*)(ws + OFF_XP);       // 25.2 MB packed
    unsigned int*  HP  = (unsigned int*)(ws + OFF_HP);       // 25.2 MB packed
    unsigned char* HN  = ws + OFF_HN;                        // fp8 hn0, 8.4 MB

    // ws re-poisoned every call -> rebuild everything (incl. flags) each time.
    prep_weights<<<384, 256, 0, stream>>>(Wz, Wr, Wh, ws, out);
    fused_pipeline<<<2072, 1024, 0, stream>>>(x, XP, HP, wpW, HN,
                                              xlen, xlab, Wo, out, FLG,
                                              Uz, Ur, Uh, Wz, Wr, Wh);
}